// Round 1
// baseline (624.254 us; speedup 1.0000x reference)
//
#include <hip/hip_runtime.h>
#include <hip/hip_bf16.h>

// Problem constants
#define NTOT 3060     // 2304 + 576 + 144 + 36 tokens across 4 scales
#define NPIX 2304     // 48*48
#define CH   256
#define NLN  589824   // 256*48*48

// ---------------------------------------------------------------------------
// K1: build xs_all [256][3060] = concat of bilinear-downsampled x at 4 scales.
// jax bilinear (antialias=False) downsample from 48 by 2/4/8 == 2-tap average:
//   48->24: rows {2o,2o+1}; 48->12: rows {4o+1,4o+2}; 48->6: rows {8o+3,8o+4}
// ---------------------------------------------------------------------------
__global__ __launch_bounds__(256) void k_downsample(const float* __restrict__ x,
                                                    float* __restrict__ xs) {
  int idx = blockIdx.x * 256 + threadIdx.x;   // c*NTOT + n
  if (idx >= CH * NTOT) return;
  int c = idx / NTOT;
  int n = idx - c * NTOT;
  const float* xc = x + c * NPIX;
  int p, Ws, s;
  if (n < 2304)      { s = 0; p = n;        Ws = 48; }
  else if (n < 2880) { s = 1; p = n - 2304; Ws = 24; }
  else if (n < 3024) { s = 2; p = n - 2880; Ws = 12; }
  else               { s = 3; p = n - 3024; Ws = 6;  }
  int oy = p / Ws, ox = p - oy * Ws;
  float v;
  if (s == 0) {
    v = xc[p];
  } else {
    int r, cc;
    if (s == 1)      { r = 2 * oy;     cc = 2 * ox;     }
    else if (s == 2) { r = 4 * oy + 1; cc = 4 * ox + 1; }
    else             { r = 8 * oy + 3; cc = 8 * ox + 3; }
    v = 0.25f * (xc[r * 48 + cc] + xc[r * 48 + cc + 1] +
                 xc[(r + 1) * 48 + cc] + xc[(r + 1) * 48 + cc + 1]);
  }
  xs[idx] = v;
}

// ---------------------------------------------------------------------------
// K2: GEMM  OUT[j][n] = sum_c A[j][c] * B[c][n] + bias[j]
// A: 256x256 row-major, B: 256x3060 row-major, OUT: 256x3060.
// 64x64 tile per block (256 thr, 4x4 per thread), K-tile 16, LDS-staged.
// blockIdx.z in {0,1,2} selects which (A,bias,OUT) triple (QKV fused).
// ---------------------------------------------------------------------------
__global__ __launch_bounds__(256) void k_gemm256(
    const float* __restrict__ A0, const float* __restrict__ A1, const float* __restrict__ A2,
    const float* __restrict__ b0, const float* __restrict__ b1, const float* __restrict__ b2,
    const float* __restrict__ Bm,
    float* __restrict__ O0, float* __restrict__ O1, float* __restrict__ O2) {
  int z = blockIdx.z;
  const float* A    = (z == 0) ? A0 : (z == 1) ? A1 : A2;
  const float* bias = (z == 0) ? b0 : (z == 1) ? b1 : b2;
  float* OUT        = (z == 0) ? O0 : (z == 1) ? O1 : O2;

  __shared__ float As[16][68];   // [k][j], row stride 68 floats (272B, 16B-aligned)
  __shared__ float Bs[16][68];   // [k][n]

  int t  = threadIdx.x;
  int j0 = blockIdx.y * 64, n0 = blockIdx.x * 64;
  int ty = t >> 4, tx = t & 15;
  int arow = t >> 2, acol4 = (t & 3) * 4;
  int nn = t & 63, kkb = t >> 6;

  float acc[4][4];
#pragma unroll
  for (int i = 0; i < 4; i++)
#pragma unroll
    for (int q = 0; q < 4; q++) acc[i][q] = 0.f;

  for (int k0 = 0; k0 < 256; k0 += 16) {
    float4 av = *(const float4*)&A[(j0 + arow) * 256 + k0 + acol4];
    float bstage[4];
#pragma unroll
    for (int r = 0; r < 4; r++) {
      int kk = kkb + r * 4;
      int n = n0 + nn;
      bstage[r] = (n < NTOT) ? Bm[(k0 + kk) * NTOT + n] : 0.f;
    }
    __syncthreads();
    As[acol4 + 0][arow] = av.x;
    As[acol4 + 1][arow] = av.y;
    As[acol4 + 2][arow] = av.z;
    As[acol4 + 3][arow] = av.w;
#pragma unroll
    for (int r = 0; r < 4; r++) Bs[kkb + r * 4][nn] = bstage[r];
    __syncthreads();
#pragma unroll
    for (int kk = 0; kk < 16; kk++) {
      float4 a = *(const float4*)&As[kk][ty * 4];
      float4 b = *(const float4*)&Bs[kk][tx * 4];
      float avv[4] = {a.x, a.y, a.z, a.w};
      float bvv[4] = {b.x, b.y, b.z, b.w};
#pragma unroll
      for (int i = 0; i < 4; i++)
#pragma unroll
        for (int q = 0; q < 4; q++) acc[i][q] += avv[i] * bvv[q];
    }
  }
#pragma unroll
  for (int i = 0; i < 4; i++) {
    int j = j0 + ty * 4 + i;
    float bb = bias[j];
#pragma unroll
    for (int q = 0; q < 4; q++) {
      int n = n0 + tx * 4 + q;
      if (n < NTOT) OUT[j * NTOT + n] = acc[i][q] + bb;
    }
  }
}

// ---------------------------------------------------------------------------
// K3: flash attention, fp32. Q/K/V/O stored [j=h*32+d][NTOT].
// Block = 256 thr = 4 waves; each block: 64 queries x 1 head x 1 scale.
// Keys split 4-ways across waves (online softmax per wave), LDS combine.
// Per-wave LDS region (2432 floats) is unioned: stage K[32x36]+V[32x36]
// during the loop, then partial acc/M/L for the combine.
// ---------------------------------------------------------------------------
__global__ __launch_bounds__(256) void k_attn(const float* __restrict__ Q,
                                              const float* __restrict__ K,
                                              const float* __restrict__ V,
                                              float* __restrict__ O) {
  __shared__ float smem[4][2432];

  const int Ns_tab[4]  = {2304, 576, 144, 36};
  const int off_tab[4] = {0, 2304, 2880, 3024};
  int sc = blockIdx.z;
  int Ns = Ns_tab[sc], off = off_tab[sc];
  int qbase = blockIdx.x * 64;
  if (qbase >= Ns) return;
  int h = blockIdx.y;
  int t = threadIdx.x;
  int w = t >> 6, lane = t & 63;
  int n = qbase + lane;
  bool vq = (n < Ns);

  const float* Qh = Q + (h * 32) * NTOT + off;
  const float* Kh = K + (h * 32) * NTOT + off;
  const float* Vh = V + (h * 32) * NTOT + off;

  float q[32];
#pragma unroll
  for (int d = 0; d < 32; d++) q[d] = vq ? Qh[d * NTOT + n] : 0.f;

  float M = -3.0e38f, L = 0.f;
  float acc[32];
#pragma unroll
  for (int d = 0; d < 32; d++) acc[d] = 0.f;

  int ntiles = (Ns + 31) >> 5;
  int tpw = (ntiles + 3) >> 2;
  int tbeg = w * tpw;
  int tend = min(tbeg + tpw, ntiles);

  float* Kl = &smem[w][0];      // [m*36 + d]
  float* Vl = &smem[w][1152];   // [m*36 + d]

  for (int tt = tbeg; tt < tend; tt++) {
    int mbase = tt * 32;
    // stage K,V tile (wave-private; 32 keys x 32 dims, stride 36)
#pragma unroll
    for (int r = 0; r < 16; r++) {
      int idx = lane + r * 64;
      int m = idx & 31, d = idx >> 5;
      int mg = mbase + m;
      float kvv = 0.f, vvv = 0.f;
      if (mg < Ns) { kvv = Kh[d * NTOT + mg]; vvv = Vh[d * NTOT + mg]; }
      Kl[m * 36 + d] = kvv;
      Vl[m * 36 + d] = vvv;
    }
    __asm__ volatile("s_waitcnt lgkmcnt(0)" ::: "memory");

    // scores
    float s[32];
#pragma unroll
    for (int m = 0; m < 32; m++) {
      const float4* kr = (const float4*)&Kl[m * 36];
      float s0 = 0.f, s1 = 0.f, s2 = 0.f, s3 = 0.f;
#pragma unroll
      for (int d4 = 0; d4 < 8; d4++) {
        float4 kv = kr[d4];
        s0 += q[d4 * 4 + 0] * kv.x;
        s1 += q[d4 * 4 + 1] * kv.y;
        s2 += q[d4 * 4 + 2] * kv.z;
        s3 += q[d4 * 4 + 3] * kv.w;
      }
      s[m] = (s0 + s1) + (s2 + s3);
    }
    int rem = Ns - mbase;
    if (rem < 32) {
#pragma unroll
      for (int m = 0; m < 32; m++)
        if (m >= rem) s[m] = -3.0e38f;
    }
    float tmax = s[0];
#pragma unroll
    for (int m = 1; m < 32; m++) tmax = fmaxf(tmax, s[m]);
    if (tmax > M) {
      float scl = __expf(M - tmax);
      L *= scl;
#pragma unroll
      for (int d = 0; d < 32; d++) acc[d] *= scl;
      M = tmax;
    }
#pragma unroll
    for (int m = 0; m < 32; m++) {
      float e = __expf(s[m] - M);
      L += e;
      const float4* vr = (const float4*)&Vl[m * 36];
#pragma unroll
      for (int d4 = 0; d4 < 8; d4++) {
        float4 vv = vr[d4];
        acc[d4 * 4 + 0] += e * vv.x;
        acc[d4 * 4 + 1] += e * vv.y;
        acc[d4 * 4 + 2] += e * vv.z;
        acc[d4 * 4 + 3] += e * vv.w;
      }
    }
  }

  // publish per-wave partials into own region (safe: wave done with its stage)
  float* my = &smem[w][0];
#pragma unroll
  for (int d4 = 0; d4 < 8; d4++) {
    float4 tmp = make_float4(acc[d4 * 4 + 0], acc[d4 * 4 + 1],
                             acc[d4 * 4 + 2], acc[d4 * 4 + 3]);
    *(float4*)&my[lane * 36 + d4 * 4] = tmp;
  }
  my[2304 + lane] = M;
  my[2368 + lane] = L;
  __syncthreads();

  // combine: thread (w, lane) handles query=lane, dims d = w*8 .. w*8+7
  if (vq) {
    float Mw[4], Lw[4];
#pragma unroll
    for (int wi = 0; wi < 4; wi++) {
      Mw[wi] = smem[wi][2304 + lane];
      Lw[wi] = smem[wi][2368 + lane];
    }
    float Mt = fmaxf(fmaxf(Mw[0], Mw[1]), fmaxf(Mw[2], Mw[3]));
    float ew[4];
    float denom = 0.f;
#pragma unroll
    for (int wi = 0; wi < 4; wi++) {
      ew[wi] = __expf(Mw[wi] - Mt);
      denom += ew[wi] * Lw[wi];
    }
    float rden = 1.f / denom;
#pragma unroll
    for (int dd = 0; dd < 8; dd++) {
      int d = w * 8 + dd;
      float num = ew[0] * smem[0][lane * 36 + d] + ew[1] * smem[1][lane * 36 + d] +
                  ew[2] * smem[2][lane * 36 + d] + ew[3] * smem[3][lane * 36 + d];
      O[(h * 32 + d) * NTOT + off + n] = num * rden;
    }
  }
}

// ---------------------------------------------------------------------------
// K4: upsample each scale's Y back to 48x48 (clamped half-pixel bilinear)
// and accumulate: outa[c][p] = Y0 + up(Y1) + up(Y2) + up(Y3)
// ---------------------------------------------------------------------------
__device__ __forceinline__ float bil4(const float* __restrict__ a, int S,
                                      int y, int x, float scale, float tr) {
  float fy = fmaf((float)y, scale, tr);
  float fx = fmaf((float)x, scale, tr);
  int iy = (int)floorf(fy); float wy = fy - (float)iy;
  int ix = (int)floorf(fx); float wx = fx - (float)ix;
  int y0 = min(max(iy, 0), S - 1);
  int y1 = min(max(iy + 1, 0), S - 1);
  int x0 = min(max(ix, 0), S - 1);
  int x1 = min(max(ix + 1, 0), S - 1);
  float v00 = a[y0 * S + x0], v01 = a[y0 * S + x1];
  float v10 = a[y1 * S + x0], v11 = a[y1 * S + x1];
  float top = v00 + wx * (v01 - v00);
  float bot = v10 + wx * (v11 - v10);
  return top + wy * (bot - top);
}

__global__ __launch_bounds__(256) void k_upacc(const float* __restrict__ Y,
                                               float* __restrict__ outa) {
  int idx = blockIdx.x * 256 + threadIdx.x;  // c*2304 + p
  if (idx >= NLN) return;
  int c = idx / NPIX;
  int p = idx - c * NPIX;
  int y = p / 48, x = p - y * 48;
  const float* Yc = Y + c * NTOT;
  float v = Yc[p];                                        // 48->48 identity
  v += bil4(Yc + 2304, 24, y, x, 0.5f,   -0.25f);
  v += bil4(Yc + 2880, 12, y, x, 0.25f,  -0.375f);
  v += bil4(Yc + 3024, 6,  y, x, 0.125f, -0.4375f);
  outa[idx] = v;
}

// ---------------------------------------------------------------------------
// K5: per-channel stats: So, Soo, Sox, Sx, Sxx  (block per channel)
// ---------------------------------------------------------------------------
__global__ __launch_bounds__(256) void k_chanstats(const float* __restrict__ outa,
                                                   const float* __restrict__ x,
                                                   float* __restrict__ st) {
  int c = blockIdx.x, t = threadIdx.x;
  float so = 0.f, soo = 0.f, sox = 0.f, sx = 0.f, sxx = 0.f;
  for (int p = t; p < NPIX; p += 256) {
    float o  = outa[c * NPIX + p];
    float xv = x[c * NPIX + p];
    so += o; soo += o * o; sox += o * xv; sx += xv; sxx += xv * xv;
  }
#pragma unroll
  for (int off = 32; off > 0; off >>= 1) {
    so  += __shfl_down(so, off, 64);
    soo += __shfl_down(soo, off, 64);
    sox += __shfl_down(sox, off, 64);
    sx  += __shfl_down(sx, off, 64);
    sxx += __shfl_down(sxx, off, 64);
  }
  __shared__ float part[4][5];
  int wv = t >> 6;
  if ((t & 63) == 0) {
    part[wv][0] = so; part[wv][1] = soo; part[wv][2] = sox;
    part[wv][3] = sx; part[wv][4] = sxx;
  }
  __syncthreads();
  if (t == 0) {
    float a0 = 0.f, a1 = 0.f, a2 = 0.f, a3 = 0.f, a4 = 0.f;
#pragma unroll
    for (int wi = 0; wi < 4; wi++) {
      a0 += part[wi][0]; a1 += part[wi][1]; a2 += part[wi][2];
      a3 += part[wi][3]; a4 += part[wi][4];
    }
    st[c] = a0; st[256 + c] = a1; st[512 + c] = a2; st[768 + c] = a3; st[1024 + c] = a4;
  }
}

// ---------------------------------------------------------------------------
// K6: single block: SE MLP (256->16 prelu ->256 sigmoid) -> cw[256];
// then analytic LN stats: mu, rsig from per-channel sums.
// ---------------------------------------------------------------------------
__global__ __launch_bounds__(256) void k_se(const float* __restrict__ st,
                                            const float* __restrict__ w1,
                                            const float* __restrict__ b1,
                                            const float* __restrict__ a1,
                                            const float* __restrict__ w2,
                                            const float* __restrict__ b2,
                                            float* __restrict__ cw,
                                            float* __restrict__ scal) {
  __shared__ float avg_s[256];
  __shared__ float h_s[16];
  __shared__ float rS[4], rSS[4];
  int t = threadIdx.x;
  float avg = st[t] * (1.f / (float)NPIX);
  avg_s[t] = avg;
  __syncthreads();
  int i = t >> 4, pp = t & 15;
  float partial = 0.f;
  for (int c = pp; c < 256; c += 16) partial += avg_s[c] * w1[i * 256 + c];
#pragma unroll
  for (int off = 8; off > 0; off >>= 1) partial += __shfl_down(partial, off, 16);
  if (pp == 0) {
    float hv = partial + b1[i];
    float al = a1[0];
    h_s[i] = hv > 0.f ? hv : al * hv;
  }
  __syncthreads();
  float s2 = b2[t];
#pragma unroll
  for (int k = 0; k < 16; k++) s2 += h_s[k] * w2[t * 16 + k];
  float cwv = 1.f / (1.f + expf(-s2));
  cw[t] = cwv;

  // analytic LN stats of g = outa*cw + x
  float S_part  = cwv * st[t] + st[768 + t];
  float SS_part = cwv * cwv * st[256 + t] + 2.f * cwv * st[512 + t] + st[1024 + t];
#pragma unroll
  for (int off = 32; off > 0; off >>= 1) {
    S_part  += __shfl_down(S_part, off, 64);
    SS_part += __shfl_down(SS_part, off, 64);
  }
  if ((t & 63) == 0) { rS[t >> 6] = S_part; rSS[t >> 6] = SS_part; }
  __syncthreads();
  if (t == 0) {
    float S = rS[0] + rS[1] + rS[2] + rS[3];
    float SS = rSS[0] + rSS[1] + rSS[2] + rSS[3];
    float mu = S / (float)NLN;
    float var = SS / (float)NLN - mu * mu;
    scal[0] = mu;
    scal[1] = rsqrtf(var + 1e-5f);
  }
}

// ---------------------------------------------------------------------------
// K7: final elementwise: gate + residual + layernorm + prelu
// ---------------------------------------------------------------------------
__global__ __launch_bounds__(256) void k_final(const float* __restrict__ outa,
                                               const float* __restrict__ x,
                                               const float* __restrict__ cw,
                                               const float* __restrict__ scal,
                                               const float* __restrict__ a2,
                                               float* __restrict__ out) {
  int idx = blockIdx.x * 256 + threadIdx.x;
  if (idx >= NLN) return;
  int c = idx / NPIX;
  float g = outa[idx] * cw[c] + x[idx];
  float v = (g - scal[0]) * scal[1];
  float al = a2[0];
  out[idx] = v > 0.f ? v : al * v;
}

// ---------------------------------------------------------------------------
extern "C" void kernel_launch(void* const* d_in, const int* in_sizes, int n_in,
                              void* d_out, int out_size, void* d_ws, size_t ws_size,
                              hipStream_t stream) {
  const float* x   = (const float*)d_in[0];
  const float* Wq  = (const float*)d_in[1];
  const float* bq  = (const float*)d_in[2];
  const float* Wk  = (const float*)d_in[3];
  const float* bk  = (const float*)d_in[4];
  const float* Wv  = (const float*)d_in[5];
  const float* bv  = (const float*)d_in[6];
  const float* Wfc = (const float*)d_in[7];
  const float* bfc = (const float*)d_in[8];
  const float* w1  = (const float*)d_in[9];
  const float* b1  = (const float*)d_in[10];
  const float* a1  = (const float*)d_in[11];
  const float* w2  = (const float*)d_in[12];
  const float* b2  = (const float*)d_in[13];
  const float* a2  = (const float*)d_in[14];

  float* ws   = (float*)d_ws;
  float* xs   = ws;                 // 256*3060
  float* Qb   = ws + 783360;
  float* Kb   = ws + 1566720;
  float* Vb   = ws + 2350080;
  float* Ob   = ws + 3133440;
  float* Yb   = ws + 3916800;
  float* outa = ws + 4700160;       // 256*2304
  float* st   = ws + 5289984;       // 5*256
  float* cwب  = ws + 5291264;       // 256
  float* scal = ws + 5291520;       // 2

  k_downsample<<<dim3((CH * NTOT + 255) / 256), 256, 0, stream>>>(x, xs);
  k_gemm256<<<dim3(48, 4, 3), 256, 0, stream>>>(Wq, Wk, Wv, bq, bk, bv, xs, Qb, Kb, Vb);
  k_attn<<<dim3(36, 8, 4), 256, 0, stream>>>(Qb, Kb, Vb, Ob);
  k_gemm256<<<dim3(48, 4, 1), 256, 0, stream>>>(Wfc, Wfc, Wfc, bfc, bfc, bfc, Ob, Yb, Yb, Yb);
  k_upacc<<<dim3(NLN / 256), 256, 0, stream>>>(Yb, outa);
  k_chanstats<<<dim3(256), 256, 0, stream>>>(outa, x, st);
  k_se<<<dim3(1), 256, 0, stream>>>(st, w1, b1, a1, w2, b2, cwب, scal);
  k_final<<<dim3(NLN / 256), 256, 0, stream>>>(outa, x, cwب, scal, a2, (float*)d_out);
}

// Round 3
// 224.844 us; speedup vs baseline: 2.7764x; 2.7764x over previous
//
#include <hip/hip_runtime.h>
#include <hip/hip_bf16.h>

// Problem constants
#define NTOT 3060     // 2304 + 576 + 144 + 36 tokens across 4 scales
#define NPIX 2304     // 48*48
#define CH   256
#define NLN  589824   // 256*48*48
#define VSTR 3072     // padded row stride (tokens) for V^T bf16 (16B-aligned rows)

typedef __attribute__((ext_vector_type(8))) short bf16x8;
typedef __attribute__((ext_vector_type(16))) float f32x16;

__device__ __forceinline__ bf16x8 ldfrag(const unsigned short* p) {
  int4 v = *reinterpret_cast<const int4*>(p);
  return __builtin_bit_cast(bf16x8, v);
}
// round-to-nearest-even f32 -> bf16 (values bounded; no NaN handling needed)
__device__ __forceinline__ unsigned f2bf(float f) {
  unsigned u = __builtin_bit_cast(unsigned, f);
  return (u + 0x7FFFu + ((u >> 16) & 1u)) >> 16;
}
// pack two floats -> u32 of 2x bf16 (a = low/elem0, b = high/elem1)
__device__ __forceinline__ unsigned pk2(float a, float b) {
  return f2bf(a) | (f2bf(b) << 16);
}
#define MFMA32(a, b, c) __builtin_amdgcn_mfma_f32_32x32x16_bf16((a), (b), (c), 0, 0, 0)

// ---------------------------------------------------------------------------
// K1: build xs_all [256][3060] = concat of bilinear-downsampled x at 4 scales.
// ---------------------------------------------------------------------------
__global__ __launch_bounds__(256) void k_downsample(const float* __restrict__ x,
                                                    float* __restrict__ xs) {
  int idx = blockIdx.x * 256 + threadIdx.x;   // c*NTOT + n
  if (idx >= CH * NTOT) return;
  int c = idx / NTOT;
  int n = idx - c * NTOT;
  const float* xc = x + c * NPIX;
  int p, Ws, s;
  if (n < 2304)      { s = 0; p = n;        Ws = 48; }
  else if (n < 2880) { s = 1; p = n - 2304; Ws = 24; }
  else if (n < 3024) { s = 2; p = n - 2880; Ws = 12; }
  else               { s = 3; p = n - 3024; Ws = 6;  }
  int oy = p / Ws, ox = p - oy * Ws;
  float v;
  if (s == 0) {
    v = xc[p];
  } else {
    int r, cc;
    if (s == 1)      { r = 2 * oy;     cc = 2 * ox;     }
    else if (s == 2) { r = 4 * oy + 1; cc = 4 * ox + 1; }
    else             { r = 8 * oy + 3; cc = 8 * ox + 3; }
    v = 0.25f * (xc[r * 48 + cc] + xc[r * 48 + cc + 1] +
                 xc[(r + 1) * 48 + cc] + xc[(r + 1) * 48 + cc + 1]);
  }
  xs[idx] = v;
}

// ---------------------------------------------------------------------------
// K2: fp32 GEMM  OUT[j][n] = sum_c A[j][c] * B[c][n] + bias[j]
// ---------------------------------------------------------------------------
__global__ __launch_bounds__(256) void k_gemm256(
    const float* __restrict__ A0, const float* __restrict__ A1, const float* __restrict__ A2,
    const float* __restrict__ b0, const float* __restrict__ b1, const float* __restrict__ b2,
    const float* __restrict__ Bm,
    float* __restrict__ O0, float* __restrict__ O1, float* __restrict__ O2) {
  int z = blockIdx.z;
  const float* A    = (z == 0) ? A0 : (z == 1) ? A1 : A2;
  const float* bias = (z == 0) ? b0 : (z == 1) ? b1 : b2;
  float* OUT        = (z == 0) ? O0 : (z == 1) ? O1 : O2;

  __shared__ float As[16][68];
  __shared__ float Bs[16][68];

  int t  = threadIdx.x;
  int j0 = blockIdx.y * 64, n0 = blockIdx.x * 64;
  int ty = t >> 4, tx = t & 15;
  int arow = t >> 2, acol4 = (t & 3) * 4;
  int nn = t & 63, kkb = t >> 6;

  float acc[4][4];
#pragma unroll
  for (int i = 0; i < 4; i++)
#pragma unroll
    for (int q = 0; q < 4; q++) acc[i][q] = 0.f;

  for (int k0 = 0; k0 < 256; k0 += 16) {
    float4 av = *(const float4*)&A[(j0 + arow) * 256 + k0 + acol4];
    float bstage[4];
#pragma unroll
    for (int r = 0; r < 4; r++) {
      int kk = kkb + r * 4;
      int n = n0 + nn;
      bstage[r] = (n < NTOT) ? Bm[(k0 + kk) * NTOT + n] : 0.f;
    }
    __syncthreads();
    As[acol4 + 0][arow] = av.x;
    As[acol4 + 1][arow] = av.y;
    As[acol4 + 2][arow] = av.z;
    As[acol4 + 3][arow] = av.w;
#pragma unroll
    for (int r = 0; r < 4; r++) Bs[kkb + r * 4][nn] = bstage[r];
    __syncthreads();
#pragma unroll
    for (int kk = 0; kk < 16; kk++) {
      float4 a = *(const float4*)&As[kk][ty * 4];
      float4 b = *(const float4*)&Bs[kk][tx * 4];
      float avv[4] = {a.x, a.y, a.z, a.w};
      float bvv[4] = {b.x, b.y, b.z, b.w};
#pragma unroll
      for (int i = 0; i < 4; i++)
#pragma unroll
        for (int q = 0; q < 4; q++) acc[i][q] += avv[i] * bvv[q];
    }
  }
#pragma unroll
  for (int i = 0; i < 4; i++) {
    int j = j0 + ty * 4 + i;
    float bb = bias[j];
#pragma unroll
    for (int q = 0; q < 4; q++) {
      int n = n0 + tx * 4 + q;
      if (n < NTOT) OUT[j * NTOT + n] = acc[i][q] + bb;
    }
  }
}

// ---------------------------------------------------------------------------
// K2b: transpose-repack Q,K: fp32 [h*32+d][NTOT] -> bf16 [h][token][32]
// one 64-token tile per block; z=0 -> Q, z=1 -> K
// ---------------------------------------------------------------------------
__global__ __launch_bounds__(256) void k_repackT(const float* __restrict__ Qb,
                                                 const float* __restrict__ Kb,
                                                 unsigned short* __restrict__ Qbf,
                                                 unsigned short* __restrict__ Kbf) {
  __shared__ float Ls[32][65];
  int t = threadIdx.x;
  int n0 = blockIdx.x * 64;
  int h  = blockIdx.y;
  const float* src = (blockIdx.z == 0) ? Qb : Kb;
  unsigned short* dst = (blockIdx.z == 0) ? Qbf : Kbf;
#pragma unroll
  for (int i = 0; i < 8; i++) {
    int idx = t + i * 256;           // 32*64
    int d = idx >> 6, tk = idx & 63;
    int n = n0 + tk;
    Ls[d][tk] = (n < NTOT) ? src[(h * 32 + d) * NTOT + n] : 0.f;
  }
  __syncthreads();
  int tk = t >> 2, dq = t & 3;
  int n = n0 + tk;
  if (n < NTOT) {
    unsigned w[4];
#pragma unroll
    for (int j = 0; j < 4; j++)
      w[j] = pk2(Ls[dq * 8 + 2 * j][tk], Ls[dq * 8 + 2 * j + 1][tk]);
    int4 out = make_int4((int)w[0], (int)w[1], (int)w[2], (int)w[3]);
    *reinterpret_cast<int4*>(&dst[((size_t)h * NTOT + n) * 32 + dq * 8]) = out;
  }
}

// ---------------------------------------------------------------------------
// K2c: cast V fp32 [j][NTOT] -> bf16 V^T [j][VSTR] (row-padded)
// ---------------------------------------------------------------------------
__global__ __launch_bounds__(256) void k_castV(const float* __restrict__ Vb,
                                               unsigned short* __restrict__ Vt) {
  int row = blockIdx.x;   // 0..255
  int t = threadIdx.x;
  for (int i = 0; i < 3; i++) {
    int c4 = t + i * 256;
    if (c4 < 765) {
      float4 v = *(const float4*)&Vb[(size_t)row * NTOT + c4 * 4];
      unsigned u0 = pk2(v.x, v.y), u1 = pk2(v.z, v.w);
      int2 out = make_int2((int)u0, (int)u1);
      *reinterpret_cast<int2*>(&Vt[(size_t)row * VSTR + c4 * 4]) = out;
    }
  }
}

// ---------------------------------------------------------------------------
// K3: bf16 MFMA flash attention, register-only (no LDS, no barriers).
// Per wave: 32 queries x all keys of one (scale, head). 4 waves/block.
// S^T = K·Q^T via mfma_32x32x16_bf16 (lane owns one query column);
// online softmax lane-local + one shfl_xor(32); P repacked to bf16 pairs
// + 8 shfl_xor(32) to form the PV B-fragment; O^T = V^T·P^T.
// ---------------------------------------------------------------------------
__global__ __launch_bounds__(256) void k_attn_mfma(const unsigned short* __restrict__ Qbf,
                                                   const unsigned short* __restrict__ Kbf,
                                                   const unsigned short* __restrict__ Vt,
                                                   float* __restrict__ Ob) {
  const int Ns_tab[4]  = {2304, 576, 144, 36};
  const int off_tab[4] = {0, 2304, 2880, 3024};

  int bid = blockIdx.x;
  int sc, head, qt;
  if (bid < 144)      { sc = 0; head = bid / 18; qt = bid - head * 18; }
  else if (bid < 184) { int b = bid - 144; sc = 1; head = b / 5; qt = b - head * 5; }
  else if (bid < 200) { int b = bid - 184; sc = 2; head = b >> 1; qt = b & 1; }
  else                { sc = 3; head = bid - 200; qt = 0; }

  int Ns = Ns_tab[sc], off = off_tab[sc];
  int t = threadIdx.x;
  int w = t >> 6, l = t & 63;
  int lq = l & 31, h2 = l >> 5;
  int qbase = qt * 128 + w * 32;
  if (qbase >= Ns) return;

  const unsigned short* Qh = Qbf + ((size_t)head * NTOT + off) * 32;
  const unsigned short* Kh = Kbf + ((size_t)head * NTOT + off) * 32;
  const unsigned short* Vh = Vt + (size_t)(head * 32) * VSTR + off;

  int qc = qbase + lq; if (qc >= Ns) qc = Ns - 1;
  const unsigned short* Qp = Qh + (size_t)qc * 32 + h2 * 8;
  bf16x8 qf0 = ldfrag(Qp);
  bf16x8 qf1 = ldfrag(Qp + 16);

  float m = -3.0e38f, L = 0.f;
  f32x16 oacc = {0,0,0,0,0,0,0,0,0,0,0,0,0,0,0,0};

  for (int kb = 0; kb < Ns; kb += 32) {
    int mt = kb + lq; if (mt >= Ns) mt = Ns - 1;
    const unsigned short* Kp = Kh + (size_t)mt * 32 + h2 * 8;
    bf16x8 kf0 = ldfrag(Kp);
    bf16x8 kf1 = ldfrag(Kp + 16);
    f32x16 sa = {0,0,0,0,0,0,0,0,0,0,0,0,0,0,0,0};
    sa = MFMA32(kf0, qf0, sa);     // S^T += K(d 0..15) · Q^T
    sa = MFMA32(kf1, qf1, sa);     // S^T += K(d 16..31) · Q^T

    float s[16];
#pragma unroll
    for (int r = 0; r < 16; r++) s[r] = sa[r];
    int rem = Ns - kb;
    if (rem < 32) {
#pragma unroll
      for (int r = 0; r < 16; r++) {
        int ko = (r & 3) + 8 * (r >> 2) + 4 * h2;
        if (ko >= rem) s[r] = -3.0e38f;
      }
    }
    float cm = s[0];
#pragma unroll
    for (int r = 1; r < 16; r++) cm = fmaxf(cm, s[r]);
    cm = fmaxf(cm, __shfl_xor(cm, 32));
    float mn = fmaxf(m, cm);
    float scl = __expf(m - mn);    // first chunk: exp(-huge) = 0
    m = mn;
    L *= scl;
#pragma unroll
    for (int r = 0; r < 16; r++) oacc[r] *= scl;

    float p[16], ls = 0.f;
#pragma unroll
    for (int r = 0; r < 16; r++) { p[r] = __expf(s[r] - m); ls += p[r]; }
    ls += __shfl_xor(ls, 32);
    L += ls;

    unsigned u[8], su[8];
#pragma unroll
    for (int g = 0; g < 8; g++) u[g] = pk2(p[2 * g], p[2 * g + 1]);
#pragma unroll
    for (int g = 0; g < 8; g++) su[g] = __shfl_xor(u[g], 32);

    int4 w0, w1;
    if (h2 == 0) {
      w0 = make_int4((int)u[0], (int)u[1], (int)su[0], (int)su[1]);
      w1 = make_int4((int)u[4], (int)u[5], (int)su[4], (int)su[5]);
    } else {
      w0 = make_int4((int)su[2], (int)su[3], (int)u[2], (int)u[3]);
      w1 = make_int4((int)su[6], (int)su[7], (int)u[6], (int)u[7]);
    }
    bf16x8 pf0 = __builtin_bit_cast(bf16x8, w0);
    bf16x8 pf1 = __builtin_bit_cast(bf16x8, w1);

    const unsigned short* Vp = Vh + (size_t)lq * VSTR + kb + h2 * 8;
    bf16x8 vf0 = ldfrag(Vp);        // keys kb .. kb+15
    bf16x8 vf1 = ldfrag(Vp + 16);   // keys kb+16 .. kb+31
    oacc = MFMA32(vf0, pf0, oacc);
    oacc = MFMA32(vf1, pf1, oacc);
  }

  int q = qbase + lq;
  if (q < Ns) {
    float rl = 1.f / L;
    float* Op = Ob + (size_t)(head * 32) * NTOT + off + q;
#pragma unroll
    for (int r = 0; r < 16; r++) {
      int dr = (r & 3) + 8 * (r >> 2) + 4 * h2;
      Op[(size_t)dr * NTOT] = oacc[r] * rl;
    }
  }
}

// ---------------------------------------------------------------------------
// K4: upsample each scale's Y back to 48x48 and accumulate
// ---------------------------------------------------------------------------
__device__ __forceinline__ float bil4(const float* __restrict__ a, int S,
                                      int y, int x, float scale, float tr) {
  float fy = fmaf((float)y, scale, tr);
  float fx = fmaf((float)x, scale, tr);
  int iy = (int)floorf(fy); float wy = fy - (float)iy;
  int ix = (int)floorf(fx); float wx = fx - (float)ix;
  int y0 = min(max(iy, 0), S - 1);
  int y1 = min(max(iy + 1, 0), S - 1);
  int x0 = min(max(ix, 0), S - 1);
  int x1 = min(max(ix + 1, 0), S - 1);
  float v00 = a[y0 * S + x0], v01 = a[y0 * S + x1];
  float v10 = a[y1 * S + x0], v11 = a[y1 * S + x1];
  float top = v00 + wx * (v01 - v00);
  float bot = v10 + wx * (v11 - v10);
  return top + wy * (bot - top);
}

__global__ __launch_bounds__(256) void k_upacc(const float* __restrict__ Y,
                                               float* __restrict__ outa) {
  int idx = blockIdx.x * 256 + threadIdx.x;
  if (idx >= NLN) return;
  int c = idx / NPIX;
  int p = idx - c * NPIX;
  int y = p / 48, x = p - y * 48;
  const float* Yc = Y + c * NTOT;
  float v = Yc[p];
  v += bil4(Yc + 2304, 24, y, x, 0.5f,   -0.25f);
  v += bil4(Yc + 2880, 12, y, x, 0.25f,  -0.375f);
  v += bil4(Yc + 3024, 6,  y, x, 0.125f, -0.4375f);
  outa[idx] = v;
}

// ---------------------------------------------------------------------------
// K5: per-channel stats: So, Soo, Sox, Sx, Sxx
// ---------------------------------------------------------------------------
__global__ __launch_bounds__(256) void k_chanstats(const float* __restrict__ outa,
                                                   const float* __restrict__ x,
                                                   float* __restrict__ st) {
  int c = blockIdx.x, t = threadIdx.x;
  float so = 0.f, soo = 0.f, sox = 0.f, sx = 0.f, sxx = 0.f;
  for (int p = t; p < NPIX; p += 256) {
    float o  = outa[c * NPIX + p];
    float xv = x[c * NPIX + p];
    so += o; soo += o * o; sox += o * xv; sx += xv; sxx += xv * xv;
  }
#pragma unroll
  for (int off = 32; off > 0; off >>= 1) {
    so  += __shfl_down(so, off, 64);
    soo += __shfl_down(soo, off, 64);
    sox += __shfl_down(sox, off, 64);
    sx  += __shfl_down(sx, off, 64);
    sxx += __shfl_down(sxx, off, 64);
  }
  __shared__ float part[4][5];
  int wv = t >> 6;
  if ((t & 63) == 0) {
    part[wv][0] = so; part[wv][1] = soo; part[wv][2] = sox;
    part[wv][3] = sx; part[wv][4] = sxx;
  }
  __syncthreads();
  if (t == 0) {
    float a0 = 0.f, a1 = 0.f, a2 = 0.f, a3 = 0.f, a4 = 0.f;
#pragma unroll
    for (int wi = 0; wi < 4; wi++) {
      a0 += part[wi][0]; a1 += part[wi][1]; a2 += part[wi][2];
      a3 += part[wi][3]; a4 += part[wi][4];
    }
    st[c] = a0; st[256 + c] = a1; st[512 + c] = a2; st[768 + c] = a3; st[1024 + c] = a4;
  }
}

// ---------------------------------------------------------------------------
// K6: SE MLP + analytic LN stats
// ---------------------------------------------------------------------------
__global__ __launch_bounds__(256) void k_se(const float* __restrict__ st,
                                            const float* __restrict__ w1,
                                            const float* __restrict__ b1,
                                            const float* __restrict__ a1,
                                            const float* __restrict__ w2,
                                            const float* __restrict__ b2,
                                            float* __restrict__ cw,
                                            float* __restrict__ scal) {
  __shared__ float avg_s[256];
  __shared__ float h_s[16];
  __shared__ float rS[4], rSS[4];
  int t = threadIdx.x;
  float avg = st[t] * (1.f / (float)NPIX);
  avg_s[t] = avg;
  __syncthreads();
  int i = t >> 4, pp = t & 15;
  float partial = 0.f;
  for (int c = pp; c < 256; c += 16) partial += avg_s[c] * w1[i * 256 + c];
#pragma unroll
  for (int off = 8; off > 0; off >>= 1) partial += __shfl_down(partial, off, 16);
  if (pp == 0) {
    float hv = partial + b1[i];
    float al = a1[0];
    h_s[i] = hv > 0.f ? hv : al * hv;
  }
  __syncthreads();
  float s2 = b2[t];
#pragma unroll
  for (int k = 0; k < 16; k++) s2 += h_s[k] * w2[t * 16 + k];
  float cwv = 1.f / (1.f + expf(-s2));
  cw[t] = cwv;

  float S_part  = cwv * st[t] + st[768 + t];
  float SS_part = cwv * cwv * st[256 + t] + 2.f * cwv * st[512 + t] + st[1024 + t];
#pragma unroll
  for (int off = 32; off > 0; off >>= 1) {
    S_part  += __shfl_down(S_part, off, 64);
    SS_part += __shfl_down(SS_part, off, 64);
  }
  if ((t & 63) == 0) { rS[t >> 6] = S_part; rSS[t >> 6] = SS_part; }
  __syncthreads();
  if (t == 0) {
    float S = rS[0] + rS[1] + rS[2] + rS[3];
    float SS = rSS[0] + rSS[1] + rSS[2] + rSS[3];
    float mu = S / (float)NLN;
    float var = SS / (float)NLN - mu * mu;
    scal[0] = mu;
    scal[1] = rsqrtf(var + 1e-5f);
  }
}

// ---------------------------------------------------------------------------
// K7: final elementwise: gate + residual + layernorm + prelu
// ---------------------------------------------------------------------------
__global__ __launch_bounds__(256) void k_final(const float* __restrict__ outa,
                                               const float* __restrict__ x,
                                               const float* __restrict__ cw,
                                               const float* __restrict__ scal,
                                               const float* __restrict__ a2,
                                               float* __restrict__ out) {
  int idx = blockIdx.x * 256 + threadIdx.x;
  if (idx >= NLN) return;
  int c = idx / NPIX;
  float g = outa[idx] * cw[c] + x[idx];
  float v = (g - scal[0]) * scal[1];
  float al = a2[0];
  out[idx] = v > 0.f ? v : al * v;
}

// ---------------------------------------------------------------------------
extern "C" void kernel_launch(void* const* d_in, const int* in_sizes, int n_in,
                              void* d_out, int out_size, void* d_ws, size_t ws_size,
                              hipStream_t stream) {
  const float* x   = (const float*)d_in[0];
  const float* Wq  = (const float*)d_in[1];
  const float* bq  = (const float*)d_in[2];
  const float* Wk  = (const float*)d_in[3];
  const float* bk  = (const float*)d_in[4];
  const float* Wv  = (const float*)d_in[5];
  const float* bv  = (const float*)d_in[6];
  const float* Wfc = (const float*)d_in[7];
  const float* bfc = (const float*)d_in[8];
  const float* w1  = (const float*)d_in[9];
  const float* b1  = (const float*)d_in[10];
  const float* a1  = (const float*)d_in[11];
  const float* w2  = (const float*)d_in[12];
  const float* b2  = (const float*)d_in[13];
  const float* a2  = (const float*)d_in[14];

  float* ws   = (float*)d_ws;
  float* xs   = ws;                 // 256*3060
  float* Qb   = ws + 783360;
  float* Kb   = ws + 1566720;
  float* Vb   = ws + 2350080;
  float* Ob   = ws + 3133440;
  float* Yb   = ws + 3916800;       // written by FC gemm (after attn)
  float* outa = ws + 4700160;       // written by upacc (after attn)
  float* st   = ws + 5289984;
  float* cwv  = ws + 5291264;
  float* scal = ws + 5291520;

  // bf16 overlays on dead regions (live only between repack and attn):
  unsigned short* Qbf = (unsigned short*)(ws + 3916800);            // in Yb region
  unsigned short* Kbf = (unsigned short*)(ws + 3916800) + 783360;   // in Yb region
  unsigned short* Vt  = (unsigned short*)(ws + 4700160);            // in outa region, 256*VSTR

  k_downsample<<<dim3((CH * NTOT + 255) / 256), 256, 0, stream>>>(x, xs);
  k_gemm256<<<dim3(48, 4, 3), 256, 0, stream>>>(Wq, Wk, Wv, bq, bk, bv, xs, Qb, Kb, Vb);
  k_repackT<<<dim3(48, 8, 2), 256, 0, stream>>>(Qb, Kb, Qbf, Kbf);
  k_castV<<<dim3(256), 256, 0, stream>>>(Vb, Vt);
  k_attn_mfma<<<dim3(208), 256, 0, stream>>>(Qbf, Kbf, Vt, Ob);
  k_gemm256<<<dim3(48, 4, 1), 256, 0, stream>>>(Wfc, Wfc, Wfc, bfc, bfc, bfc, Ob, Yb, Yb, Yb);
  k_upacc<<<dim3(NLN / 256), 256, 0, stream>>>(Yb, outa);
  k_chanstats<<<dim3(256), 256, 0, stream>>>(outa, x, st);
  k_se<<<dim3(1), 256, 0, stream>>>(st, w1, b1, a1, w2, b2, cwv, scal);
  k_final<<<dim3(NLN / 256), 256, 0, stream>>>(outa, x, cwv, scal, a2, (float*)d_out);
}

// Round 5
// 207.360 us; speedup vs baseline: 3.0105x; 1.0843x over previous
//
#include <hip/hip_runtime.h>
#include <hip/hip_bf16.h>

// Problem constants
#define NTOT 3060     // 2304 + 576 + 144 + 36 tokens across 4 scales
#define NPIX 2304     // 48*48
#define CH   256
#define NLN  589824   // 256*48*48
#define VSTR 3072     // padded row stride (tokens) for V^T bf16 (16B-aligned rows)

// Partial-buffer float offsets inside the dead pool ws[0 .. 3133440)
// (xs, Qb, Kb, Vb regions are all dead by the time k_attn_mfma runs)
#define P0_OFF   0          // 4*8*2304*32 = 2359296
#define P1_OFF   2359296    // 2*8*576*32  = 294912
#define PM0_OFF  2654208    // 4*8*2304    = 73728
#define PL0_OFF  2727936    // 73728
#define PM1_OFF  2801664    // 2*8*576     = 9216
#define PL1_OFF  2810880    // 9216  (ends 2820096 < 3133440)

typedef __attribute__((ext_vector_type(8))) short bf16x8;
typedef __attribute__((ext_vector_type(16))) float f32x16;

__device__ __forceinline__ bf16x8 ldfrag(const unsigned short* p) {
  int4 v = *reinterpret_cast<const int4*>(p);
  return __builtin_bit_cast(bf16x8, v);
}
// round-to-nearest-even f32 -> bf16 (values bounded; no NaN handling needed)
__device__ __forceinline__ unsigned f2bf(float f) {
  unsigned u = __builtin_bit_cast(unsigned, f);
  return (u + 0x7FFFu + ((u >> 16) & 1u)) >> 16;
}
__device__ __forceinline__ unsigned pk2(float a, float b) {
  return f2bf(a) | (f2bf(b) << 16);
}
#define MFMA32(a, b, c) __builtin_amdgcn_mfma_f32_32x32x16_bf16((a), (b), (c), 0, 0, 0)

// ---------------------------------------------------------------------------
// K1: build xs_all [256][3060] = concat of bilinear-downsampled x at 4 scales.
// ---------------------------------------------------------------------------
__global__ __launch_bounds__(256) void k_downsample(const float* __restrict__ x,
                                                    float* __restrict__ xs) {
  int idx = blockIdx.x * 256 + threadIdx.x;   // c*NTOT + n
  if (idx >= CH * NTOT) return;
  int c = idx / NTOT;
  int n = idx - c * NTOT;
  const float* xc = x + c * NPIX;
  int p, Ws, s;
  if (n < 2304)      { s = 0; p = n;        Ws = 48; }
  else if (n < 2880) { s = 1; p = n - 2304; Ws = 24; }
  else if (n < 3024) { s = 2; p = n - 2880; Ws = 12; }
  else               { s = 3; p = n - 3024; Ws = 6;  }
  int oy = p / Ws, ox = p - oy * Ws;
  float v;
  if (s == 0) {
    v = xc[p];
  } else {
    int r, cc;
    if (s == 1)      { r = 2 * oy;     cc = 2 * ox;     }
    else if (s == 2) { r = 4 * oy + 1; cc = 4 * ox + 1; }
    else             { r = 8 * oy + 3; cc = 8 * ox + 3; }
    v = 0.25f * (xc[r * 48 + cc] + xc[r * 48 + cc + 1] +
                 xc[(r + 1) * 48 + cc] + xc[(r + 1) * 48 + cc + 1]);
  }
  xs[idx] = v;
}

// ---------------------------------------------------------------------------
// K2: fp32 GEMM  OUT[j][n] = sum_c A[j][c] * B[c][n] + bias[j]
// ---------------------------------------------------------------------------
__global__ __launch_bounds__(256) void k_gemm256(
    const float* __restrict__ A0, const float* __restrict__ A1, const float* __restrict__ A2,
    const float* __restrict__ b0, const float* __restrict__ b1, const float* __restrict__ b2,
    const float* __restrict__ Bm,
    float* __restrict__ O0, float* __restrict__ O1, float* __restrict__ O2) {
  int z = blockIdx.z;
  const float* A    = (z == 0) ? A0 : (z == 1) ? A1 : A2;
  const float* bias = (z == 0) ? b0 : (z == 1) ? b1 : b2;
  float* OUT        = (z == 0) ? O0 : (z == 1) ? O1 : O2;

  __shared__ float As[16][68];
  __shared__ float Bs[16][68];

  int t  = threadIdx.x;
  int j0 = blockIdx.y * 64, n0 = blockIdx.x * 64;
  int ty = t >> 4, tx = t & 15;
  int arow = t >> 2, acol4 = (t & 3) * 4;
  int nn = t & 63, kkb = t >> 6;

  float acc[4][4];
#pragma unroll
  for (int i = 0; i < 4; i++)
#pragma unroll
    for (int q = 0; q < 4; q++) acc[i][q] = 0.f;

  for (int k0 = 0; k0 < 256; k0 += 16) {
    float4 av = *(const float4*)&A[(j0 + arow) * 256 + k0 + acol4];
    float bstage[4];
#pragma unroll
    for (int r = 0; r < 4; r++) {
      int kk = kkb + r * 4;
      int n = n0 + nn;
      bstage[r] = (n < NTOT) ? Bm[(k0 + kk) * NTOT + n] : 0.f;
    }
    __syncthreads();
    As[acol4 + 0][arow] = av.x;
    As[acol4 + 1][arow] = av.y;
    As[acol4 + 2][arow] = av.z;
    As[acol4 + 3][arow] = av.w;
#pragma unroll
    for (int r = 0; r < 4; r++) Bs[kkb + r * 4][nn] = bstage[r];
    __syncthreads();
#pragma unroll
    for (int kk = 0; kk < 16; kk++) {
      float4 a = *(const float4*)&As[kk][ty * 4];
      float4 b = *(const float4*)&Bs[kk][tx * 4];
      float avv[4] = {a.x, a.y, a.z, a.w};
      float bvv[4] = {b.x, b.y, b.z, b.w};
#pragma unroll
      for (int i = 0; i < 4; i++)
#pragma unroll
        for (int q = 0; q < 4; q++) acc[i][q] += avv[i] * bvv[q];
    }
  }
#pragma unroll
  for (int i = 0; i < 4; i++) {
    int j = j0 + ty * 4 + i;
    float bb = bias[j];
#pragma unroll
    for (int q = 0; q < 4; q++) {
      int n = n0 + tx * 4 + q;
      if (n < NTOT) OUT[j * NTOT + n] = acc[i][q] + bb;
    }
  }
}

// ---------------------------------------------------------------------------
// K2b: transpose-repack Q,K: fp32 [h*32+d][NTOT] -> bf16 [h][token][32]
// ---------------------------------------------------------------------------
__global__ __launch_bounds__(256) void k_repackT(const float* __restrict__ Qb,
                                                 const float* __restrict__ Kb,
                                                 unsigned short* __restrict__ Qbf,
                                                 unsigned short* __restrict__ Kbf) {
  __shared__ float Ls[32][65];
  int t = threadIdx.x;
  int n0 = blockIdx.x * 64;
  int h  = blockIdx.y;
  const float* src = (blockIdx.z == 0) ? Qb : Kb;
  unsigned short* dst = (blockIdx.z == 0) ? Qbf : Kbf;
#pragma unroll
  for (int i = 0; i < 8; i++) {
    int idx = t + i * 256;           // 32*64
    int d = idx >> 6, tk = idx & 63;
    int n = n0 + tk;
    Ls[d][tk] = (n < NTOT) ? src[(h * 32 + d) * NTOT + n] : 0.f;
  }
  __syncthreads();
  int tk = t >> 2, dq = t & 3;
  int n = n0 + tk;
  if (n < NTOT) {
    unsigned w[4];
#pragma unroll
    for (int j = 0; j < 4; j++)
      w[j] = pk2(Ls[dq * 8 + 2 * j][tk], Ls[dq * 8 + 2 * j + 1][tk]);
    int4 out = make_int4((int)w[0], (int)w[1], (int)w[2], (int)w[3]);
    *reinterpret_cast<int4*>(&dst[((size_t)h * NTOT + n) * 32 + dq * 8]) = out;
  }
}

// ---------------------------------------------------------------------------
// K2c: cast V fp32 [j][NTOT] -> bf16 V^T [j][VSTR] (row-padded)
// ---------------------------------------------------------------------------
__global__ __launch_bounds__(256) void k_castV(const float* __restrict__ Vb,
                                               unsigned short* __restrict__ Vt) {
  int row = blockIdx.x;   // 0..255
  int t = threadIdx.x;
  for (int i = 0; i < 3; i++) {
    int c4 = t + i * 256;
    if (c4 < 765) {
      float4 v = *(const float4*)&Vb[(size_t)row * NTOT + c4 * 4];
      unsigned u0 = pk2(v.x, v.y), u1 = pk2(v.z, v.w);
      int2 out = make_int2((int)u0, (int)u1);
      *reinterpret_cast<int2*>(&Vt[(size_t)row * VSTR + c4 * 4]) = out;
    }
  }
}

// ---------------------------------------------------------------------------
// K3: bf16 MFMA flash attention with flash-decoding split-K.
// Scale 0 split 4-way (576 keys each), scale 1 split 2-way, scales 2/3 whole.
// Split blocks write unnormalized partial O + (m, L) to Pb; k_combine merges.
// K-tile software prefetch + early V-load hide L2 latency under softmax.
// ---------------------------------------------------------------------------
__global__ __launch_bounds__(256) void k_attn_mfma(const unsigned short* __restrict__ Qbf,
                                                   const unsigned short* __restrict__ Kbf,
                                                   const unsigned short* __restrict__ Vt,
                                                   float* __restrict__ Ob,
                                                   float* __restrict__ Pb) {
  const int Ns_tab[4]  = {2304, 576, 144, 36};
  const int off_tab[4] = {0, 2304, 2880, 3024};

  int bid = blockIdx.x;
  int sc, head, qt, sp, nsp;
  if (bid < 576)      { int qtb = bid >> 2; sp = bid & 3;  nsp = 4; sc = 0; head = qtb / 18; qt = qtb - head * 18; }
  else if (bid < 656) { int b = bid - 576; int qtb = b >> 1; sp = b & 1; nsp = 2; sc = 1; head = qtb / 5; qt = qtb - head * 5; }
  else if (bid < 672) { int b = bid - 656; sc = 2; head = b >> 1; qt = b & 1; sp = 0; nsp = 1; }
  else                { sc = 3; head = bid - 672; qt = 0; sp = 0; nsp = 1; }

  int Ns = Ns_tab[sc], off = off_tab[sc];
  int t = threadIdx.x;
  int w = t >> 6, l = t & 63;
  int lq = l & 31, h2 = l >> 5;
  int qbase = qt * 128 + w * 32;
  if (qbase >= Ns) return;

  int chunk = Ns / nsp;
  int kbeg = sp * chunk, kend = kbeg + chunk;

  const unsigned short* Qh = Qbf + ((size_t)head * NTOT + off) * 32;
  const unsigned short* Kh = Kbf + ((size_t)head * NTOT + off) * 32;
  const unsigned short* Vh = Vt + (size_t)(head * 32) * VSTR + off;

  int qc = qbase + lq; if (qc >= Ns) qc = Ns - 1;
  const unsigned short* Qp = Qh + (size_t)qc * 32 + h2 * 8;
  bf16x8 qf0 = ldfrag(Qp);
  bf16x8 qf1 = ldfrag(Qp + 16);

  float m = -3.0e38f, L = 0.f;
  f32x16 oacc = {0,0,0,0,0,0,0,0,0,0,0,0,0,0,0,0};

  // prefetch first K tile
  int mt0 = kbeg + lq; if (mt0 >= Ns) mt0 = Ns - 1;
  const unsigned short* Kp0 = Kh + (size_t)mt0 * 32 + h2 * 8;
  bf16x8 kf0n = ldfrag(Kp0);
  bf16x8 kf1n = ldfrag(Kp0 + 16);

  for (int kb = kbeg; kb < kend; kb += 32) {
    bf16x8 kf0 = kf0n, kf1 = kf1n;
    // early V load (latency hides under softmax below)
    const unsigned short* Vp = Vh + (size_t)lq * VSTR + kb + h2 * 8;
    bf16x8 vf0 = ldfrag(Vp);
    bf16x8 vf1 = ldfrag(Vp + 16);
    // prefetch next K tile
    int kb2 = kb + 32;
    if (kb2 < kend) {
      int mt = kb2 + lq; if (mt >= Ns) mt = Ns - 1;
      const unsigned short* Kp = Kh + (size_t)mt * 32 + h2 * 8;
      kf0n = ldfrag(Kp);
      kf1n = ldfrag(Kp + 16);
    }

    f32x16 sa = {0,0,0,0,0,0,0,0,0,0,0,0,0,0,0,0};
    sa = MFMA32(kf0, qf0, sa);     // S^T += K(d 0..15) · Q^T
    sa = MFMA32(kf1, qf1, sa);     // S^T += K(d 16..31) · Q^T

    float s[16];
#pragma unroll
    for (int r = 0; r < 16; r++) s[r] = sa[r];
    int rem = kend - kb;
    if (rem < 32) {
#pragma unroll
      for (int r = 0; r < 16; r++) {
        int ko = (r & 3) + 8 * (r >> 2) + 4 * h2;
        if (ko >= rem) s[r] = -3.0e38f;
      }
    }
    float cm = s[0];
#pragma unroll
    for (int r = 1; r < 16; r++) cm = fmaxf(cm, s[r]);
    cm = fmaxf(cm, __shfl_xor(cm, 32));
    float mn = fmaxf(m, cm);
    float scl = __expf(m - mn);    // first chunk: exp(-huge) = 0
    m = mn;
    L *= scl;
#pragma unroll
    for (int r = 0; r < 16; r++) oacc[r] *= scl;

    float p[16], ls = 0.f;
#pragma unroll
    for (int r = 0; r < 16; r++) { p[r] = __expf(s[r] - m); ls += p[r]; }
    ls += __shfl_xor(ls, 32);
    L += ls;

    unsigned u[8], su[8];
#pragma unroll
    for (int g = 0; g < 8; g++) u[g] = pk2(p[2 * g], p[2 * g + 1]);
#pragma unroll
    for (int g = 0; g < 8; g++) su[g] = __shfl_xor(u[g], 32);

    int4 w0, w1;
    if (h2 == 0) {
      w0 = make_int4((int)u[0], (int)u[1], (int)su[0], (int)su[1]);
      w1 = make_int4((int)u[4], (int)u[5], (int)su[4], (int)su[5]);
    } else {
      w0 = make_int4((int)su[2], (int)su[3], (int)u[2], (int)u[3]);
      w1 = make_int4((int)su[6], (int)su[7], (int)u[6], (int)u[7]);
    }
    bf16x8 pf0 = __builtin_bit_cast(bf16x8, w0);
    bf16x8 pf1 = __builtin_bit_cast(bf16x8, w1);

    oacc = MFMA32(vf0, pf0, oacc);
    oacc = MFMA32(vf1, pf1, oacc);
  }

  int q = qbase + lq;
  if (q < Ns) {
    if (nsp == 1) {
      float rl = 1.f / L;
      float* Op = Ob + (size_t)(head * 32) * NTOT + off + q;
#pragma unroll
      for (int r = 0; r < 16; r++) {
        int dr = (r & 3) + 8 * (r >> 2) + 4 * h2;
        Op[(size_t)dr * NTOT] = oacc[r] * rl;
      }
    } else {
      int qs = (sc == 0) ? 2304 : 576;
      float* P  = (sc == 0) ? Pb + P0_OFF  : Pb + P1_OFF;
      float* Pm = (sc == 0) ? Pb + PM0_OFF : Pb + PM1_OFF;
      float* PL = (sc == 0) ? Pb + PL0_OFF : Pb + PL1_OFF;
      size_t row = (size_t)(sp * 8 + head) * qs + q;
      float* Prow = P + row * 32;
#pragma unroll
      for (int g = 0; g < 4; g++) {
        float4 v = make_float4(oacc[4 * g + 0], oacc[4 * g + 1],
                               oacc[4 * g + 2], oacc[4 * g + 3]);
        *(float4*)&Prow[g * 8 + 4 * h2] = v;
      }
      if (h2 == 0) { Pm[row] = m; PL[row] = L; }
    }
  }
}

// ---------------------------------------------------------------------------
// K3b: combine split-K partials -> Ob (scale 0: 4 splits, scale 1: 2 splits)
// thread = (head, q); wave-coalesced strided writes into Ob rows.
// ---------------------------------------------------------------------------
__global__ __launch_bounds__(256) void k_combine(const float* __restrict__ Pb,
                                                 float* __restrict__ Ob) {
  int tid = blockIdx.x * 256 + threadIdx.x;
  int h, q, off, nsp, qs;
  const float* P; const float* Pm; const float* PL;
  if (tid < 18432) {
    h = tid / 2304; q = tid - h * 2304; off = 0; nsp = 4; qs = 2304;
    P = Pb + P0_OFF; Pm = Pb + PM0_OFF; PL = Pb + PL0_OFF;
  } else if (tid < 23040) {
    int b = tid - 18432;
    h = b / 576; q = b - h * 576; off = 2304; nsp = 2; qs = 576;
    P = Pb + P1_OFF; Pm = Pb + PM1_OFF; PL = Pb + PL1_OFF;
  } else return;

  float mv[4], lv[4];
  float M = -3.0e38f;
  for (int s = 0; s < nsp; s++) {
    size_t row = (size_t)(s * 8 + h) * qs + q;
    mv[s] = Pm[row]; lv[s] = PL[row];
    M = fmaxf(M, mv[s]);
  }
  float e[4], denom = 0.f;
  for (int s = 0; s < nsp; s++) { e[s] = __expf(mv[s] - M); denom += e[s] * lv[s]; }
  float rden = 1.f / denom;

  float* Op = Ob + (size_t)(h * 32) * NTOT + off + q;
#pragma unroll
  for (int d4 = 0; d4 < 8; d4++) {
    float4 acc = make_float4(0.f, 0.f, 0.f, 0.f);
    for (int s = 0; s < nsp; s++) {
      size_t row = (size_t)(s * 8 + h) * qs + q;
      float4 v = *(const float4*)&P[row * 32 + d4 * 4];
      acc.x += e[s] * v.x; acc.y += e[s] * v.y;
      acc.z += e[s] * v.z; acc.w += e[s] * v.w;
    }
    Op[(size_t)(d4 * 4 + 0) * NTOT] = acc.x * rden;
    Op[(size_t)(d4 * 4 + 1) * NTOT] = acc.y * rden;
    Op[(size_t)(d4 * 4 + 2) * NTOT] = acc.z * rden;
    Op[(size_t)(d4 * 4 + 3) * NTOT] = acc.w * rden;
  }
}

// ---------------------------------------------------------------------------
// K4: upsample each scale's Y back to 48x48 and accumulate
// ---------------------------------------------------------------------------
__device__ __forceinline__ float bil4(const float* __restrict__ a, int S,
                                      int y, int x, float scale, float tr) {
  float fy = fmaf((float)y, scale, tr);
  float fx = fmaf((float)x, scale, tr);
  int iy = (int)floorf(fy); float wy = fy - (float)iy;
  int ix = (int)floorf(fx); float wx = fx - (float)ix;
  int y0 = min(max(iy, 0), S - 1);
  int y1 = min(max(iy + 1, 0), S - 1);
  int x0 = min(max(ix, 0), S - 1);
  int x1 = min(max(ix + 1, 0), S - 1);
  float v00 = a[y0 * S + x0], v01 = a[y0 * S + x1];
  float v10 = a[y1 * S + x0], v11 = a[y1 * S + x1];
  float top = v00 + wx * (v01 - v00);
  float bot = v10 + wx * (v11 - v10);
  return top + wy * (bot - top);
}

__global__ __launch_bounds__(256) void k_upacc(const float* __restrict__ Y,
                                               float* __restrict__ outa) {
  int idx = blockIdx.x * 256 + threadIdx.x;
  if (idx >= NLN) return;
  int c = idx / NPIX;
  int p = idx - c * NPIX;
  int y = p / 48, x = p - y * 48;
  const float* Yc = Y + c * NTOT;
  float v = Yc[p];
  v += bil4(Yc + 2304, 24, y, x, 0.5f,   -0.25f);
  v += bil4(Yc + 2880, 12, y, x, 0.25f,  -0.375f);
  v += bil4(Yc + 3024, 6,  y, x, 0.125f, -0.4375f);
  outa[idx] = v;
}

// ---------------------------------------------------------------------------
// K5: per-channel stats: So, Soo, Sox, Sx, Sxx
// ---------------------------------------------------------------------------
__global__ __launch_bounds__(256) void k_chanstats(const float* __restrict__ outa,
                                                   const float* __restrict__ x,
                                                   float* __restrict__ st) {
  int c = blockIdx.x, t = threadIdx.x;
  float so = 0.f, soo = 0.f, sox = 0.f, sx = 0.f, sxx = 0.f;
  for (int p = t; p < NPIX; p += 256) {
    float o  = outa[c * NPIX + p];
    float xv = x[c * NPIX + p];
    so += o; soo += o * o; sox += o * xv; sx += xv; sxx += xv * xv;
  }
#pragma unroll
  for (int off = 32; off > 0; off >>= 1) {
    so  += __shfl_down(so, off, 64);
    soo += __shfl_down(soo, off, 64);
    sox += __shfl_down(sox, off, 64);
    sx  += __shfl_down(sx, off, 64);
    sxx += __shfl_down(sxx, off, 64);
  }
  __shared__ float part[4][5];
  int wv = t >> 6;
  if ((t & 63) == 0) {
    part[wv][0] = so; part[wv][1] = soo; part[wv][2] = sox;
    part[wv][3] = sx; part[wv][4] = sxx;
  }
  __syncthreads();
  if (t == 0) {
    float a0 = 0.f, a1 = 0.f, a2 = 0.f, a3 = 0.f, a4 = 0.f;
#pragma unroll
    for (int wi = 0; wi < 4; wi++) {
      a0 += part[wi][0]; a1 += part[wi][1]; a2 += part[wi][2];
      a3 += part[wi][3]; a4 += part[wi][4];
    }
    st[c] = a0; st[256 + c] = a1; st[512 + c] = a2; st[768 + c] = a3; st[1024 + c] = a4;
  }
}

// ---------------------------------------------------------------------------
// K6: SE MLP + analytic LN stats
// ---------------------------------------------------------------------------
__global__ __launch_bounds__(256) void k_se(const float* __restrict__ st,
                                            const float* __restrict__ w1,
                                            const float* __restrict__ b1,
                                            const float* __restrict__ a1,
                                            const float* __restrict__ w2,
                                            const float* __restrict__ b2,
                                            float* __restrict__ cw,
                                            float* __restrict__ scal) {
  __shared__ float avg_s[256];
  __shared__ float h_s[16];
  __shared__ float rS[4], rSS[4];
  int t = threadIdx.x;
  float avg = st[t] * (1.f / (float)NPIX);
  avg_s[t] = avg;
  __syncthreads();
  int i = t >> 4, pp = t & 15;
  float partial = 0.f;
  for (int c = pp; c < 256; c += 16) partial += avg_s[c] * w1[i * 256 + c];
#pragma unroll
  for (int off = 8; off > 0; off >>= 1) partial += __shfl_down(partial, off, 16);
  if (pp == 0) {
    float hv = partial + b1[i];
    float al = a1[0];
    h_s[i] = hv > 0.f ? hv : al * hv;
  }
  __syncthreads();
  float s2 = b2[t];
#pragma unroll
  for (int k = 0; k < 16; k++) s2 += h_s[k] * w2[t * 16 + k];
  float cwv = 1.f / (1.f + expf(-s2));
  cw[t] = cwv;

  float S_part  = cwv * st[t] + st[768 + t];
  float SS_part = cwv * cwv * st[256 + t] + 2.f * cwv * st[512 + t] + st[1024 + t];
#pragma unroll
  for (int off = 32; off > 0; off >>= 1) {
    S_part  += __shfl_down(S_part, off, 64);
    SS_part += __shfl_down(SS_part, off, 64);
  }
  if ((t & 63) == 0) { rS[t >> 6] = S_part; rSS[t >> 6] = SS_part; }
  __syncthreads();
  if (t == 0) {
    float S = rS[0] + rS[1] + rS[2] + rS[3];
    float SS = rSS[0] + rSS[1] + rSS[2] + rSS[3];
    float mu = S / (float)NLN;
    float var = SS / (float)NLN - mu * mu;
    scal[0] = mu;
    scal[1] = rsqrtf(var + 1e-5f);
  }
}

// ---------------------------------------------------------------------------
// K7: final elementwise: gate + residual + layernorm + prelu
// ---------------------------------------------------------------------------
__global__ __launch_bounds__(256) void k_final(const float* __restrict__ outa,
                                               const float* __restrict__ x,
                                               const float* __restrict__ cw,
                                               const float* __restrict__ scal,
                                               const float* __restrict__ a2,
                                               float* __restrict__ out) {
  int idx = blockIdx.x * 256 + threadIdx.x;
  if (idx >= NLN) return;
  int c = idx / NPIX;
  float g = outa[idx] * cw[c] + x[idx];
  float v = (g - scal[0]) * scal[1];
  float al = a2[0];
  out[idx] = v > 0.f ? v : al * v;
}

// ---------------------------------------------------------------------------
extern "C" void kernel_launch(void* const* d_in, const int* in_sizes, int n_in,
                              void* d_out, int out_size, void* d_ws, size_t ws_size,
                              hipStream_t stream) {
  const float* x   = (const float*)d_in[0];
  const float* Wq  = (const float*)d_in[1];
  const float* bq  = (const float*)d_in[2];
  const float* Wk  = (const float*)d_in[3];
  const float* bk  = (const float*)d_in[4];
  const float* Wv  = (const float*)d_in[5];
  const float* bv  = (const float*)d_in[6];
  const float* Wfc = (const float*)d_in[7];
  const float* bfc = (const float*)d_in[8];
  const float* w1  = (const float*)d_in[9];
  const float* b1  = (const float*)d_in[10];
  const float* a1  = (const float*)d_in[11];
  const float* w2  = (const float*)d_in[12];
  const float* b2  = (const float*)d_in[13];
  const float* a2  = (const float*)d_in[14];

  float* ws   = (float*)d_ws;
  float* xs   = ws;                 // 256*3060              (dead after QKV gemm)
  float* Qb   = ws + 783360;        //                        (dead after repackT)
  float* Kb   = ws + 1566720;       //                        (dead after repackT)
  float* Vb   = ws + 2350080;       //                        (dead after castV)
  float* Ob   = ws + 3133440;
  float* Yb   = ws + 3916800;       // holds Qbf/Kbf during attn, then FC output
  float* outa = ws + 4700160;       // holds Vt during attn, then upacc output
  float* st   = ws + 5289984;
  float* cwv  = ws + 5291264;
  float* scal = ws + 5291520;

  // bf16 overlays on dead regions (live only between repack and attn):
  unsigned short* Qbf = (unsigned short*)(ws + 3916800);            // in Yb region
  unsigned short* Kbf = (unsigned short*)(ws + 3916800) + 783360;   // in Yb region
  unsigned short* Vt  = (unsigned short*)(ws + 4700160);            // in outa region
  // split-K partial pool overlays xs/Qb/Kb/Vb (all dead by attn time):
  float* Pb = ws;

  k_downsample<<<dim3((CH * NTOT + 255) / 256), 256, 0, stream>>>(x, xs);
  k_gemm256<<<dim3(48, 4, 3), 256, 0, stream>>>(Wq, Wk, Wv, bq, bk, bv, xs, Qb, Kb, Vb);
  k_repackT<<<dim3(48, 8, 2), 256, 0, stream>>>(Qb, Kb, Qbf, Kbf);
  k_castV<<<dim3(256), 256, 0, stream>>>(Vb, Vt);
  k_attn_mfma<<<dim3(680), 256, 0, stream>>>(Qbf, Kbf, Vt, Ob, Pb);
  k_combine<<<dim3(90), 256, 0, stream>>>(Pb, Ob);
  k_gemm256<<<dim3(48, 4, 1), 256, 0, stream>>>(Wfc, Wfc, Wfc, bfc, bfc, bfc, Ob, Yb, Yb, Yb);
  k_upacc<<<dim3(NLN / 256), 256, 0, stream>>>(Yb, outa);
  k_chanstats<<<dim3(256), 256, 0, stream>>>(outa, x, st);
  k_se<<<dim3(1), 256, 0, stream>>>(st, w1, b1, a1, w2, b2, cwv, scal);
  k_final<<<dim3(NLN / 256), 256, 0, stream>>>(outa, x, cwv, scal, a2, (float*)d_out);
}

// Round 6
// 173.509 us; speedup vs baseline: 3.5978x; 1.1951x over previous
//
#include <hip/hip_runtime.h>
#include <hip/hip_bf16.h>

// Problem constants
#define NTOT 3060     // 2304 + 576 + 144 + 36 tokens across 4 scales
#define NPIX 2304     // 48*48
#define CH   256
#define NLN  589824   // 256*48*48
#define VSTR 3072     // padded row stride (tokens) for V^T bf16 (16B-aligned rows)

// Split-K partial pool (float offsets in ws[0..3133440), dead pool during attn)
#define P0_OFF   0          // 4*8*2304*32 = 2359296
#define P1_OFF   2359296    // 2*8*576*32  = 294912
#define PM0_OFF  2654208    // 73728
#define PL0_OFF  2727936    // 73728
#define PM1_OFF  2801664    // 9216
#define PL1_OFF  2810880    // 9216  (ends 2820096 < 3133440)

typedef __attribute__((ext_vector_type(8))) short bf16x8;
typedef __attribute__((ext_vector_type(16))) float f32x16;

__device__ __forceinline__ bf16x8 ldfrag(const unsigned short* p) {
  int4 v = *reinterpret_cast<const int4*>(p);
  return __builtin_bit_cast(bf16x8, v);
}
// round-to-nearest-even f32 -> bf16
__device__ __forceinline__ unsigned f2bf(float f) {
  unsigned u = __builtin_bit_cast(unsigned, f);
  return (u + 0x7FFFu + ((u >> 16) & 1u)) >> 16;
}
__device__ __forceinline__ unsigned pk2(float a, float b) {
  return f2bf(a) | (f2bf(b) << 16);
}
#define MFMA32(a, b, c) __builtin_amdgcn_mfma_f32_32x32x16_bf16((a), (b), (c), 0, 0, 0)

// ---------------------------------------------------------------------------
// K0: cast 4 weight matrices fp32 -> bf16, concatenated [Wq|Wk|Wv|Wfc]
// ---------------------------------------------------------------------------
__global__ __launch_bounds__(256) void k_castW(const float* __restrict__ Wq,
                                               const float* __restrict__ Wk,
                                               const float* __restrict__ Wv,
                                               const float* __restrict__ Wfc,
                                               unsigned* __restrict__ Wb) {
  int i = blockIdx.x * 256 + threadIdx.x;   // u32 index, total 131072
  int m = i >> 15;                          // 32768 u32 per matrix
  int r = i & 32767;
  const float* src = (m == 0) ? Wq : (m == 1) ? Wk : (m == 2) ? Wv : Wfc;
  float2 v = *(const float2*)&src[(size_t)r * 2];
  Wb[i] = pk2(v.x, v.y);
}

// ---------------------------------------------------------------------------
// K1: downsample x -> xsT [token][256] bf16 (GEMM B-operand layout).
// Each thread: one token, 16 channels, 16B-packed writes.
// ---------------------------------------------------------------------------
__global__ __launch_bounds__(256) void k_downsample(const float* __restrict__ x,
                                                    unsigned short* __restrict__ xsT) {
  int t = threadIdx.x;
  int n = blockIdx.x * 64 + (t & 63);
  int cb = blockIdx.y * 64 + (t >> 6) * 16;   // 16 channels per thread
  if (n >= NTOT) return;
  int p, Ws, s;
  if (n < 2304)      { s = 0; p = n;        Ws = 48; }
  else if (n < 2880) { s = 1; p = n - 2304; Ws = 24; }
  else if (n < 3024) { s = 2; p = n - 2880; Ws = 12; }
  else               { s = 3; p = n - 3024; Ws = 6;  }
  int oy = p / Ws, ox = p - oy * Ws;
  int b0; bool avg = (s != 0);
  if (s == 0) b0 = p;
  else {
    int r, cc;
    if (s == 1)      { r = 2 * oy;     cc = 2 * ox;     }
    else if (s == 2) { r = 4 * oy + 1; cc = 4 * ox + 1; }
    else             { r = 8 * oy + 3; cc = 8 * ox + 3; }
    b0 = r * 48 + cc;
  }
#pragma unroll
  for (int i0 = 0; i0 < 16; i0 += 8) {
    unsigned u[4];
#pragma unroll
    for (int jj = 0; jj < 4; jj++) {
      float v[2];
#pragma unroll
      for (int e = 0; e < 2; e++) {
        int c = cb + i0 + jj * 2 + e;
        const float* xc = x + (size_t)c * NPIX;
        v[e] = avg ? 0.25f * (xc[b0] + xc[b0 + 1] + xc[b0 + 48] + xc[b0 + 49])
                   : xc[b0];
      }
      u[jj] = pk2(v[0], v[1]);
    }
    *(int4*)&xsT[(size_t)n * 256 + cb + i0] = make_int4((int)u[0], (int)u[1],
                                                        (int)u[2], (int)u[3]);
  }
}

// ---------------------------------------------------------------------------
// K2: QKV GEMM via MFMA. OUT[j][n] = sum_c W[j][c]*x[c][n] + bias[j].
// Register-only; wave = 32j x 32n tile, K=256 in 16 MFMA.
// z=0 -> Qbf [h][n][32], z=1 -> Kbf [h][n][32], z=2 -> Vt [j][VSTR]+n (bf16).
// ---------------------------------------------------------------------------
__global__ __launch_bounds__(256) void k_qkv_mfma(const unsigned short* __restrict__ Wb,
                                                  const float* __restrict__ bq,
                                                  const float* __restrict__ bk,
                                                  const float* __restrict__ bv,
                                                  const unsigned short* __restrict__ xsT,
                                                  unsigned short* __restrict__ Qbf,
                                                  unsigned short* __restrict__ Kbf,
                                                  unsigned short* __restrict__ Vt) {
  int z = blockIdx.z, h = blockIdx.y;
  int j0 = h * 32;
  const unsigned short* W = Wb + (size_t)z * 65536;
  const float* bias = (z == 0) ? bq : (z == 1) ? bk : bv;
  int t = threadIdx.x, w = t >> 6, l = t & 63, lq = l & 31, h2 = l >> 5;
  int n = blockIdx.x * 128 + w * 32 + lq;
  int nc = min(n, NTOT - 1);

  bf16x8 bfr[16];
#pragma unroll
  for (int kk = 0; kk < 16; kk++)
    bfr[kk] = ldfrag(&xsT[(size_t)nc * 256 + kk * 16 + h2 * 8]);

  f32x16 acc = {0,0,0,0,0,0,0,0,0,0,0,0,0,0,0,0};
#pragma unroll
  for (int kk = 0; kk < 16; kk++) {
    bf16x8 af = ldfrag(&W[(size_t)(j0 + lq) * 256 + kk * 16 + h2 * 8]);
    acc = MFMA32(af, bfr[kk], acc);
  }

  float4 bi[4];
#pragma unroll
  for (int g = 0; g < 4; g++) bi[g] = *(const float4*)&bias[j0 + 4 * h2 + 8 * g];

  if (n < NTOT) {
    if (z < 2) {
      unsigned short* dst = ((z == 0) ? Qbf : Kbf) + ((size_t)h * NTOT + n) * 32;
#pragma unroll
      for (int g = 0; g < 4; g++) {
        unsigned p0 = pk2(acc[4 * g + 0] + bi[g].x, acc[4 * g + 1] + bi[g].y);
        unsigned p1 = pk2(acc[4 * g + 2] + bi[g].z, acc[4 * g + 3] + bi[g].w);
        *(int2*)&dst[4 * h2 + 8 * g] = make_int2((int)p0, (int)p1);
      }
    } else {
#pragma unroll
      for (int g = 0; g < 4; g++) {
        float bb[4] = {bi[g].x, bi[g].y, bi[g].z, bi[g].w};
#pragma unroll
        for (int q = 0; q < 4; q++) {
          int d = 4 * h2 + 8 * g + q;
          Vt[(size_t)(j0 + d) * VSTR + n] = (unsigned short)f2bf(acc[4 * g + q] + bb[q]);
        }
      }
    }
  }
}

// ---------------------------------------------------------------------------
// K3: bf16 MFMA flash attention with split-K (4-way sc0, 2-way sc1).
// Whole-scale blocks write O^T directly to Obf [token][256] bf16;
// split blocks write fp32 partials to Pb, merged by k_combine.
// ---------------------------------------------------------------------------
__global__ __launch_bounds__(256) void k_attn_mfma(const unsigned short* __restrict__ Qbf,
                                                   const unsigned short* __restrict__ Kbf,
                                                   const unsigned short* __restrict__ Vt,
                                                   unsigned short* __restrict__ Obf,
                                                   float* __restrict__ Pb) {
  const int Ns_tab[4]  = {2304, 576, 144, 36};
  const int off_tab[4] = {0, 2304, 2880, 3024};

  int bid = blockIdx.x;
  int sc, head, qt, sp, nsp;
  if (bid < 576)      { int qtb = bid >> 2; sp = bid & 3;  nsp = 4; sc = 0; head = qtb / 18; qt = qtb - head * 18; }
  else if (bid < 656) { int b = bid - 576; int qtb = b >> 1; sp = b & 1; nsp = 2; sc = 1; head = qtb / 5; qt = qtb - head * 5; }
  else if (bid < 672) { int b = bid - 656; sc = 2; head = b >> 1; qt = b & 1; sp = 0; nsp = 1; }
  else                { sc = 3; head = bid - 672; qt = 0; sp = 0; nsp = 1; }

  int Ns = Ns_tab[sc], off = off_tab[sc];
  int t = threadIdx.x;
  int w = t >> 6, l = t & 63;
  int lq = l & 31, h2 = l >> 5;
  int qbase = qt * 128 + w * 32;
  if (qbase >= Ns) return;

  int chunk = Ns / nsp;
  int kbeg = sp * chunk, kend = kbeg + chunk;

  const unsigned short* Qh = Qbf + ((size_t)head * NTOT + off) * 32;
  const unsigned short* Kh = Kbf + ((size_t)head * NTOT + off) * 32;
  const unsigned short* Vh = Vt + (size_t)(head * 32) * VSTR + off;

  int qc = qbase + lq; if (qc >= Ns) qc = Ns - 1;
  const unsigned short* Qp = Qh + (size_t)qc * 32 + h2 * 8;
  bf16x8 qf0 = ldfrag(Qp);
  bf16x8 qf1 = ldfrag(Qp + 16);

  float m = -3.0e38f, L = 0.f;
  f32x16 oacc = {0,0,0,0,0,0,0,0,0,0,0,0,0,0,0,0};

  int mt0 = kbeg + lq; if (mt0 >= Ns) mt0 = Ns - 1;
  const unsigned short* Kp0 = Kh + (size_t)mt0 * 32 + h2 * 8;
  bf16x8 kf0n = ldfrag(Kp0);
  bf16x8 kf1n = ldfrag(Kp0 + 16);

  for (int kb = kbeg; kb < kend; kb += 32) {
    bf16x8 kf0 = kf0n, kf1 = kf1n;
    const unsigned short* Vp = Vh + (size_t)lq * VSTR + kb + h2 * 8;
    bf16x8 vf0 = ldfrag(Vp);
    bf16x8 vf1 = ldfrag(Vp + 16);
    int kb2 = kb + 32;
    if (kb2 < kend) {
      int mt = kb2 + lq; if (mt >= Ns) mt = Ns - 1;
      const unsigned short* Kp = Kh + (size_t)mt * 32 + h2 * 8;
      kf0n = ldfrag(Kp);
      kf1n = ldfrag(Kp + 16);
    }

    f32x16 sa = {0,0,0,0,0,0,0,0,0,0,0,0,0,0,0,0};
    sa = MFMA32(kf0, qf0, sa);
    sa = MFMA32(kf1, qf1, sa);

    float s[16];
#pragma unroll
    for (int r = 0; r < 16; r++) s[r] = sa[r];
    int rem = kend - kb;
    if (rem < 32) {
#pragma unroll
      for (int r = 0; r < 16; r++) {
        int ko = (r & 3) + 8 * (r >> 2) + 4 * h2;
        if (ko >= rem) s[r] = -3.0e38f;
      }
    }
    float cm = s[0];
#pragma unroll
    for (int r = 1; r < 16; r++) cm = fmaxf(cm, s[r]);
    cm = fmaxf(cm, __shfl_xor(cm, 32));
    float mn = fmaxf(m, cm);
    float scl = __expf(m - mn);
    m = mn;
    L *= scl;
#pragma unroll
    for (int r = 0; r < 16; r++) oacc[r] *= scl;

    float p[16], ls = 0.f;
#pragma unroll
    for (int r = 0; r < 16; r++) { p[r] = __expf(s[r] - m); ls += p[r]; }
    ls += __shfl_xor(ls, 32);
    L += ls;

    unsigned u[8], su[8];
#pragma unroll
    for (int g = 0; g < 8; g++) u[g] = pk2(p[2 * g], p[2 * g + 1]);
#pragma unroll
    for (int g = 0; g < 8; g++) su[g] = __shfl_xor(u[g], 32);

    int4 w0, w1;
    if (h2 == 0) {
      w0 = make_int4((int)u[0], (int)u[1], (int)su[0], (int)su[1]);
      w1 = make_int4((int)u[4], (int)u[5], (int)su[4], (int)su[5]);
    } else {
      w0 = make_int4((int)su[2], (int)su[3], (int)u[2], (int)u[3]);
      w1 = make_int4((int)su[6], (int)su[7], (int)u[6], (int)u[7]);
    }
    bf16x8 pf0 = __builtin_bit_cast(bf16x8, w0);
    bf16x8 pf1 = __builtin_bit_cast(bf16x8, w1);

    oacc = MFMA32(vf0, pf0, oacc);
    oacc = MFMA32(vf1, pf1, oacc);
  }

  int q = qbase + lq;
  if (q < Ns) {
    if (nsp == 1) {
      float rl = 1.f / L;
      unsigned short* dst = Obf + (size_t)(off + q) * 256 + head * 32;
#pragma unroll
      for (int g = 0; g < 4; g++) {
        unsigned p0 = pk2(oacc[4 * g + 0] * rl, oacc[4 * g + 1] * rl);
        unsigned p1 = pk2(oacc[4 * g + 2] * rl, oacc[4 * g + 3] * rl);
        *(int2*)&dst[4 * h2 + 8 * g] = make_int2((int)p0, (int)p1);
      }
    } else {
      int qs = (sc == 0) ? 2304 : 576;
      float* P  = (sc == 0) ? Pb + P0_OFF  : Pb + P1_OFF;
      float* Pm = (sc == 0) ? Pb + PM0_OFF : Pb + PM1_OFF;
      float* PL = (sc == 0) ? Pb + PL0_OFF : Pb + PL1_OFF;
      size_t row = (size_t)(sp * 8 + head) * qs + q;
      float* Prow = P + row * 32;
#pragma unroll
      for (int g = 0; g < 4; g++) {
        float4 v = make_float4(oacc[4 * g + 0], oacc[4 * g + 1],
                               oacc[4 * g + 2], oacc[4 * g + 3]);
        *(float4*)&Prow[g * 8 + 4 * h2] = v;
      }
      if (h2 == 0) { Pm[row] = m; PL[row] = L; }
    }
  }
}

// ---------------------------------------------------------------------------
// K3b: combine split-K partials -> Obf [token][256] bf16
// ---------------------------------------------------------------------------
__global__ __launch_bounds__(256) void k_combine(const float* __restrict__ Pb,
                                                 unsigned short* __restrict__ Obf) {
  int tid = blockIdx.x * 256 + threadIdx.x;
  int h, q, off, nsp, qs;
  const float* P; const float* Pm; const float* PL;
  if (tid < 18432) {
    h = tid / 2304; q = tid - h * 2304; off = 0; nsp = 4; qs = 2304;
    P = Pb + P0_OFF; Pm = Pb + PM0_OFF; PL = Pb + PL0_OFF;
  } else if (tid < 23040) {
    int b = tid - 18432;
    h = b / 576; q = b - h * 576; off = 2304; nsp = 2; qs = 576;
    P = Pb + P1_OFF; Pm = Pb + PM1_OFF; PL = Pb + PL1_OFF;
  } else return;

  float mv[4], lv[4];
  float M = -3.0e38f;
  for (int s = 0; s < nsp; s++) {
    size_t row = (size_t)(s * 8 + h) * qs + q;
    mv[s] = Pm[row]; lv[s] = PL[row];
    M = fmaxf(M, mv[s]);
  }
  float e[4], denom = 0.f;
  for (int s = 0; s < nsp; s++) { e[s] = __expf(mv[s] - M); denom += e[s] * lv[s]; }
  float rden = 1.f / denom;

  unsigned short* dst = Obf + (size_t)(off + q) * 256 + h * 32;
#pragma unroll
  for (int d4 = 0; d4 < 8; d4++) {
    float4 acc = make_float4(0.f, 0.f, 0.f, 0.f);
    for (int s = 0; s < nsp; s++) {
      size_t row = (size_t)(s * 8 + h) * qs + q;
      float4 v = *(const float4*)&P[row * 32 + d4 * 4];
      acc.x += e[s] * v.x; acc.y += e[s] * v.y;
      acc.z += e[s] * v.z; acc.w += e[s] * v.w;
    }
    unsigned p0 = pk2(acc.x * rden, acc.y * rden);
    unsigned p1 = pk2(acc.z * rden, acc.w * rden);
    *(int2*)&dst[d4 * 4] = make_int2((int)p0, (int)p1);
  }
}

// ---------------------------------------------------------------------------
// K4: FC GEMM via MFMA: Yb[j][n] = sum_c Wfc[j][c]*O[c][n] + bfc[j] (fp32 out)
// ---------------------------------------------------------------------------
__global__ __launch_bounds__(256) void k_fc_mfma(const unsigned short* __restrict__ Wfcb,
                                                 const float* __restrict__ bfc,
                                                 const unsigned short* __restrict__ Obf,
                                                 float* __restrict__ Yb) {
  int j0 = blockIdx.y * 32;
  int t = threadIdx.x, w = t >> 6, l = t & 63, lq = l & 31, h2 = l >> 5;
  int n = blockIdx.x * 128 + w * 32 + lq;
  int nc = min(n, NTOT - 1);

  bf16x8 bfr[16];
#pragma unroll
  for (int kk = 0; kk < 16; kk++)
    bfr[kk] = ldfrag(&Obf[(size_t)nc * 256 + kk * 16 + h2 * 8]);

  f32x16 acc = {0,0,0,0,0,0,0,0,0,0,0,0,0,0,0,0};
#pragma unroll
  for (int kk = 0; kk < 16; kk++) {
    bf16x8 af = ldfrag(&Wfcb[(size_t)(j0 + lq) * 256 + kk * 16 + h2 * 8]);
    acc = MFMA32(af, bfr[kk], acc);
  }

  float4 bi[4];
#pragma unroll
  for (int g = 0; g < 4; g++) bi[g] = *(const float4*)&bfc[j0 + 4 * h2 + 8 * g];

  if (n < NTOT) {
#pragma unroll
    for (int g = 0; g < 4; g++) {
      float bb[4] = {bi[g].x, bi[g].y, bi[g].z, bi[g].w};
#pragma unroll
      for (int q = 0; q < 4; q++) {
        int d = 4 * h2 + 8 * g + q;
        Yb[(size_t)(j0 + d) * NTOT + n] = acc[4 * g + q] + bb[q];
      }
    }
  }
}

// ---------------------------------------------------------------------------
// K5: upsample each scale's Y back to 48x48 and accumulate
// ---------------------------------------------------------------------------
__device__ __forceinline__ float bil4(const float* __restrict__ a, int S,
                                      int y, int x, float scale, float tr) {
  float fy = fmaf((float)y, scale, tr);
  float fx = fmaf((float)x, scale, tr);
  int iy = (int)floorf(fy); float wy = fy - (float)iy;
  int ix = (int)floorf(fx); float wx = fx - (float)ix;
  int y0 = min(max(iy, 0), S - 1);
  int y1 = min(max(iy + 1, 0), S - 1);
  int x0 = min(max(ix, 0), S - 1);
  int x1 = min(max(ix + 1, 0), S - 1);
  float v00 = a[y0 * S + x0], v01 = a[y0 * S + x1];
  float v10 = a[y1 * S + x0], v11 = a[y1 * S + x1];
  float top = v00 + wx * (v01 - v00);
  float bot = v10 + wx * (v11 - v10);
  return top + wy * (bot - top);
}

__global__ __launch_bounds__(256) void k_upacc(const float* __restrict__ Y,
                                               float* __restrict__ outa) {
  int idx = blockIdx.x * 256 + threadIdx.x;
  if (idx >= NLN) return;
  int c = idx / NPIX;
  int p = idx - c * NPIX;
  int y = p / 48, x = p - y * 48;
  const float* Yc = Y + c * NTOT;
  float v = Yc[p];
  v += bil4(Yc + 2304, 24, y, x, 0.5f,   -0.25f);
  v += bil4(Yc + 2880, 12, y, x, 0.25f,  -0.375f);
  v += bil4(Yc + 3024, 6,  y, x, 0.125f, -0.4375f);
  outa[idx] = v;
}

// ---------------------------------------------------------------------------
// K6: per-channel stats: So, Soo, Sox, Sx, Sxx
// ---------------------------------------------------------------------------
__global__ __launch_bounds__(256) void k_chanstats(const float* __restrict__ outa,
                                                   const float* __restrict__ x,
                                                   float* __restrict__ st) {
  int c = blockIdx.x, t = threadIdx.x;
  float so = 0.f, soo = 0.f, sox = 0.f, sx = 0.f, sxx = 0.f;
  for (int p = t; p < NPIX; p += 256) {
    float o  = outa[c * NPIX + p];
    float xv = x[c * NPIX + p];
    so += o; soo += o * o; sox += o * xv; sx += xv; sxx += xv * xv;
  }
#pragma unroll
  for (int off = 32; off > 0; off >>= 1) {
    so  += __shfl_down(so, off, 64);
    soo += __shfl_down(soo, off, 64);
    sox += __shfl_down(sox, off, 64);
    sx  += __shfl_down(sx, off, 64);
    sxx += __shfl_down(sxx, off, 64);
  }
  __shared__ float part[4][5];
  int wv = t >> 6;
  if ((t & 63) == 0) {
    part[wv][0] = so; part[wv][1] = soo; part[wv][2] = sox;
    part[wv][3] = sx; part[wv][4] = sxx;
  }
  __syncthreads();
  if (t == 0) {
    float a0 = 0.f, a1 = 0.f, a2 = 0.f, a3 = 0.f, a4 = 0.f;
#pragma unroll
    for (int wi = 0; wi < 4; wi++) {
      a0 += part[wi][0]; a1 += part[wi][1]; a2 += part[wi][2];
      a3 += part[wi][3]; a4 += part[wi][4];
    }
    st[c] = a0; st[256 + c] = a1; st[512 + c] = a2; st[768 + c] = a3; st[1024 + c] = a4;
  }
}

// ---------------------------------------------------------------------------
// K7: SE MLP + analytic LN stats
// ---------------------------------------------------------------------------
__global__ __launch_bounds__(256) void k_se(const float* __restrict__ st,
                                            const float* __restrict__ w1,
                                            const float* __restrict__ b1,
                                            const float* __restrict__ a1,
                                            const float* __restrict__ w2,
                                            const float* __restrict__ b2,
                                            float* __restrict__ cw,
                                            float* __restrict__ scal) {
  __shared__ float avg_s[256];
  __shared__ float h_s[16];
  __shared__ float rS[4], rSS[4];
  int t = threadIdx.x;
  float avg = st[t] * (1.f / (float)NPIX);
  avg_s[t] = avg;
  __syncthreads();
  int i = t >> 4, pp = t & 15;
  float partial = 0.f;
  for (int c = pp; c < 256; c += 16) partial += avg_s[c] * w1[i * 256 + c];
#pragma unroll
  for (int off = 8; off > 0; off >>= 1) partial += __shfl_down(partial, off, 16);
  if (pp == 0) {
    float hv = partial + b1[i];
    float al = a1[0];
    h_s[i] = hv > 0.f ? hv : al * hv;
  }
  __syncthreads();
  float s2 = b2[t];
#pragma unroll
  for (int k = 0; k < 16; k++) s2 += h_s[k] * w2[t * 16 + k];
  float cwv = 1.f / (1.f + expf(-s2));
  cw[t] = cwv;

  float S_part  = cwv * st[t] + st[768 + t];
  float SS_part = cwv * cwv * st[256 + t] + 2.f * cwv * st[512 + t] + st[1024 + t];
#pragma unroll
  for (int off = 32; off > 0; off >>= 1) {
    S_part  += __shfl_down(S_part, off, 64);
    SS_part += __shfl_down(SS_part, off, 64);
  }
  if ((t & 63) == 0) { rS[t >> 6] = S_part; rSS[t >> 6] = SS_part; }
  __syncthreads();
  if (t == 0) {
    float S = rS[0] + rS[1] + rS[2] + rS[3];
    float SS = rSS[0] + rSS[1] + rSS[2] + rSS[3];
    float mu = S / (float)NLN;
    float var = SS / (float)NLN - mu * mu;
    scal[0] = mu;
    scal[1] = rsqrtf(var + 1e-5f);
  }
}

// ---------------------------------------------------------------------------
// K8: final elementwise: gate + residual + layernorm + prelu
// ---------------------------------------------------------------------------
__global__ __launch_bounds__(256) void k_final(const float* __restrict__ outa,
                                               const float* __restrict__ x,
                                               const float* __restrict__ cw,
                                               const float* __restrict__ scal,
                                               const float* __restrict__ a2,
                                               float* __restrict__ out) {
  int idx = blockIdx.x * 256 + threadIdx.x;
  if (idx >= NLN) return;
  int c = idx / NPIX;
  float g = outa[idx] * cw[c] + x[idx];
  float v = (g - scal[0]) * scal[1];
  float al = a2[0];
  out[idx] = v > 0.f ? v : al * v;
}

// ---------------------------------------------------------------------------
extern "C" void kernel_launch(void* const* d_in, const int* in_sizes, int n_in,
                              void* d_out, int out_size, void* d_ws, size_t ws_size,
                              hipStream_t stream) {
  const float* x   = (const float*)d_in[0];
  const float* Wq  = (const float*)d_in[1];
  const float* bq  = (const float*)d_in[2];
  const float* Wk  = (const float*)d_in[3];
  const float* bk  = (const float*)d_in[4];
  const float* Wv  = (const float*)d_in[5];
  const float* bv  = (const float*)d_in[6];
  const float* Wfc = (const float*)d_in[7];
  const float* bfc = (const float*)d_in[8];
  const float* w1  = (const float*)d_in[9];
  const float* b1  = (const float*)d_in[10];
  const float* a1  = (const float*)d_in[11];
  const float* w2  = (const float*)d_in[12];
  const float* b2  = (const float*)d_in[13];
  const float* a2  = (const float*)d_in[14];

  float* ws = (float*)d_ws;
  // ws[0..3133440): xsT bf16 (dead after QKV gemm), then split-K partial pool Pb
  unsigned short* xsT = (unsigned short*)ws;            // 783360 u16
  float* Pb = ws;
  // ws[3133440..3916800): Obf (bf16 O^T) + Wb (4x bf16 weights)
  unsigned short* Obf = (unsigned short*)(ws + 3133440);          // 783360 u16
  unsigned short* Wb  = (unsigned short*)(ws + 3525120);          // 262144 u16
  // ws[3916800..4700160): Qbf/Kbf during attn, then Yb (FC output fp32)
  unsigned short* Qbf = (unsigned short*)(ws + 3916800);
  unsigned short* Kbf = Qbf + 783360;
  float* Yb = ws + 3916800;
  // ws[4700160..5289984): Vt during attn, then outa
  unsigned short* Vt = (unsigned short*)(ws + 4700160);           // 256*3072 u16
  float* outa = ws + 4700160;
  float* st   = ws + 5289984;
  float* cwv  = ws + 5291264;
  float* scal = ws + 5291520;

  k_castW<<<dim3(512), 256, 0, stream>>>(Wq, Wk, Wv, Wfc, (unsigned*)Wb);
  k_downsample<<<dim3(48, 4), 256, 0, stream>>>(x, xsT);
  k_qkv_mfma<<<dim3(24, 8, 3), 256, 0, stream>>>(Wb, bq, bk, bv, xsT, Qbf, Kbf, Vt);
  k_attn_mfma<<<dim3(680), 256, 0, stream>>>(Qbf, Kbf, Vt, Obf, Pb);
  k_combine<<<dim3(90), 256, 0, stream>>>(Pb, Obf);
  k_fc_mfma<<<dim3(24, 8), 256, 0, stream>>>(Wb + 196608, bfc, Obf, Yb);
  k_upacc<<<dim3(NLN / 256), 256, 0, stream>>>(Yb, outa);
  k_chanstats<<<dim3(256), 256, 0, stream>>>(outa, x, st);
  k_se<<<dim3(1), 256, 0, stream>>>(st, w1, b1, a1, w2, b2, cwv, scal);
  k_final<<<dim3(NLN / 256), 256, 0, stream>>>(outa, x, cwv, scal, a2, (float*)d_out);
}